// Round 2
// baseline (1923.407 us; speedup 1.0000x reference)
//
#include <hip/hip_runtime.h>
#include <hip/hip_bf16.h>

#define BDIM 2
#define TDIM 2048
#define DDIM 1024
#define HH 4
#define KD 512
#define VD 1024
#define DK 128
#define DV 256
#define NC 32
#define CHUNKC 64
#define MTOT (BDIM*TDIM)   // 4096

// ---------------- generic tiled GEMM: C[M,N] = A[M,K] @ B[K,N] (all fp32) ----------------
__global__ __launch_bounds__(256) void gemm64(const float* __restrict__ A,
                                              const float* __restrict__ Bw,
                                              float* __restrict__ C,
                                              int M, int N, int K) {
  __shared__ float As[64][17];
  __shared__ float Bs[16][65];
  const int tx = threadIdx.x, ty = threadIdx.y;
  const int tid = ty*16 + tx;
  const int row0 = blockIdx.y*64, col0 = blockIdx.x*64;
  float acc[4][4] = {};
  for (int k0 = 0; k0 < K; k0 += 16) {
    #pragma unroll
    for (int i = 0; i < 4; ++i) {
      int idx = tid + 256*i;
      int r = idx >> 4, cc = idx & 15;
      As[r][cc] = A[(size_t)(row0+r)*K + k0 + cc];
    }
    #pragma unroll
    for (int i = 0; i < 4; ++i) {
      int idx = tid + 256*i;
      int r = idx >> 6, cc = idx & 63;
      Bs[r][cc] = Bw[(size_t)(k0+r)*N + col0 + cc];
    }
    __syncthreads();
    #pragma unroll
    for (int kk = 0; kk < 16; ++kk) {
      float a[4], bb[4];
      #pragma unroll
      for (int i = 0; i < 4; ++i) a[i] = As[ty*4+i][kk];
      #pragma unroll
      for (int j = 0; j < 4; ++j) bb[j] = Bs[kk][tx*4+j];
      #pragma unroll
      for (int i = 0; i < 4; ++i)
        #pragma unroll
        for (int j = 0; j < 4; ++j) acc[i][j] += a[i]*bb[j];
    }
    __syncthreads();
  }
  #pragma unroll
  for (int i = 0; i < 4; ++i)
    #pragma unroll
    for (int j = 0; j < 4; ++j)
      C[(size_t)(row0+ty*4+i)*N + col0 + tx*4 + j] = acc[i][j];
}

// ---------------- low-rank: xlr[M,16] = x[M,1024] @ Wgk1[1024,16] ----------------
__global__ void lowrank_kernel(const float* __restrict__ x, const float* __restrict__ W1,
                               float* __restrict__ xlr) {
  int t = blockIdx.x*256 + threadIdx.x;   // MTOT*16 threads
  int m = t >> 4, j = t & 15;
  float s = 0.f;
  for (int kk = 0; kk < DDIM; ++kk)
    s += x[(size_t)m*DDIM + kk] * W1[kk*16 + j];
  xlr[t] = s;
}

// ---------------- gk = log_sigmoid(xlr@Wgk2 + b)/16 ----------------
__global__ void gk_kernel(const float* __restrict__ xlr, const float* __restrict__ W2,
                          const float* __restrict__ bias, float* __restrict__ G) {
  int t = blockIdx.x*256 + threadIdx.x;  // MTOT*KD threads
  int m = t >> 9, n = t & 511;
  float s = bias[n];
  #pragma unroll
  for (int r = 0; r < 16; ++r) s += xlr[m*16 + r] * W2[r*KD + n];
  // log_sigmoid(s) = min(s,0) - log1p(exp(-|s|))
  float ls = fminf(s, 0.f) - log1pf(expf(-fabsf(s)));
  G[t] = ls * (1.0f/16.0f);
}

// ---------------- in-chunk cumsum (in place) ----------------
__global__ void cumsum_kernel(float* __restrict__ G) {
  int t = blockIdx.x*256 + threadIdx.x;  // BDIM*NC*KD = 32768 threads
  int col = t & 511;
  int bn = t >> 9;                        // b*NC + nc
  int nc = bn & 31, b = bn >> 5;
  size_t base = ((size_t)(b*TDIM + nc*CHUNKC))*KD + col;
  float acc = 0.f;
  for (int c = 0; c < CHUNKC; ++c) {
    acc += G[base + (size_t)c*KD];
    G[base + (size_t)c*KD] = acc;
  }
}

// ---------------- sequential chunk scan: writes S_prev for every chunk ----------------
// grid: 32 blocks = (b*H+h)*4 + v_slice; S slice 128x64 in registers (32 f32/thread)
__global__ __launch_bounds__(256) void scan_kernel(const float* __restrict__ kbuf,
                                                   const float* __restrict__ vbuf,
                                                   const float* __restrict__ G,
                                                   float* __restrict__ Sprev) {
  const int bh = blockIdx.x >> 2;     // b*H + h
  const int vs = blockIdx.x & 3;
  const int b = bh >> 2, h = bh & 3;
  const int t = threadIdx.x;
  const int vc = t & 63;
  const int kr0 = (t >> 6) * 32;
  __shared__ float kbar[CHUNKC][DK];
  __shared__ float glast[DK];
  __shared__ float decay[DK];
  float S[32];
  #pragma unroll
  for (int i = 0; i < 32; ++i) S[i] = 0.f;
  const int vcol = h*DV + vs*64 + vc;
  for (int nc = 0; nc < NC; ++nc) {
    const size_t rowbase = ((size_t)(b*TDIM + nc*CHUNKC))*KD + h*DK;
    if (t < DK) {
      float gl = G[rowbase + (size_t)63*KD + t];
      glast[t] = gl;
      decay[t] = expf(gl);
    }
    __syncthreads();
    for (int i = 0; i < 32; ++i) {
      int idx = t + 256*i;
      int c = idx >> 7, kk = idx & 127;
      size_t off = rowbase + (size_t)c*KD + kk;
      kbar[c][kk] = kbuf[off] * expf(glast[kk] - G[off]);
    }
    __syncthreads();
    // write state BEFORE update (S_prev for this chunk)
    float* sp = Sprev + ((size_t)nc*8 + bh)*((size_t)DK*DV);
    #pragma unroll
    for (int i = 0; i < 32; ++i)
      sp[(size_t)(kr0+i)*DV + vs*64 + vc] = S[i];
    #pragma unroll
    for (int i = 0; i < 32; ++i) S[i] *= decay[kr0+i];
    for (int c = 0; c < CHUNKC; ++c) {
      float vv = vbuf[((size_t)(b*TDIM + nc*CHUNKC + c))*VD + vcol];
      #pragma unroll
      for (int i = 0; i < 32; ++i)
        S[i] += kbar[c][kr0+i] * vv;
    }
    __syncthreads();
  }
}

// ---------------- per-chunk output: o_inter + tril(A)@v, RMSNorm, silu gate ----------------
// grid: 256 blocks = nc*8 + b*4 + h
// LDS: qg 32KB + union(kg 32KB | A 16KB) = 64KB exactly.
__global__ __launch_bounds__(256) void out_kernel(const float* __restrict__ qbuf,
                                                  const float* __restrict__ kbuf,
                                                  const float* __restrict__ vbuf,
                                                  const float* __restrict__ G,
                                                  const float* __restrict__ Sprev,
                                                  const float* __restrict__ gbuf,
                                                  const float* __restrict__ gnw,
                                                  float* __restrict__ obuf) {
  const int blk = blockIdx.x;
  const int h = blk & 3, b = (blk >> 2) & 1, nc = blk >> 3;
  const int t = threadIdx.x;
  __shared__ float qg[CHUNKC][DK];
  __shared__ union { float kg[CHUNKC][DK]; float A[CHUNKC][CHUNKC]; } u;
  const float scale = 0.088388347648318447f;  // 128^-0.5
  const size_t rowbase = ((size_t)(b*TDIM + nc*CHUNKC))*KD + h*DK;
  // stage qg (plain) and kg (XOR-swizzled column) as fp32
  for (int i = 0; i < 32; ++i) {
    int idx = t + 256*i;
    int c = idx >> 7, kk = idx & 127;
    size_t off = rowbase + (size_t)c*KD + kk;
    float g = G[off];
    qg[c][kk] = qbuf[off] * expf(g) * scale;
    u.kg[c][kk ^ (c & 31)] = kbuf[off] * expf(-g);
  }
  __syncthreads();
  // A = tril(qg @ kg^T) into registers (16 entries/thread), then overwrite kg's LDS
  float areg[16];
  #pragma unroll
  for (int i = 0; i < 16; ++i) {
    int idx = t + 256*i;
    int c = idx >> 6, j = idx & 63;
    float s = 0.f;
    if (j <= c) {
      int sw = j & 31;
      #pragma unroll 8
      for (int kk = 0; kk < DK; ++kk)
        s += qg[c][kk] * u.kg[j][kk ^ sw];
    }
    areg[i] = s;
  }
  __syncthreads();
  #pragma unroll
  for (int i = 0; i < 16; ++i) {
    int idx = t + 256*i;
    int c = idx >> 6, j = idx & 63;
    u.A[c][j] = areg[i];
  }
  __syncthreads();
  const int c = t >> 2, vb = t & 3;
  const int v0 = vb*64;
  float o[64];
  #pragma unroll
  for (int vi = 0; vi < 64; ++vi) o[vi] = 0.f;
  const float* Sp = Sprev + (size_t)blk*((size_t)DK*DV);
  for (int kk = 0; kk < DK; ++kk) {
    float qv = qg[c][kk];
    const float* srow = Sp + (size_t)kk*DV + v0;
    #pragma unroll
    for (int vi = 0; vi < 64; ++vi) o[vi] += qv * srow[vi];
  }
  for (int j = 0; j <= c; ++j) {
    float a = u.A[c][j];
    const float* vrow = vbuf + ((size_t)(b*TDIM + nc*CHUNKC + j))*VD + h*DV + v0;
    #pragma unroll
    for (int vi = 0; vi < 64; ++vi) o[vi] += a * vrow[vi];
  }
  // RMSNorm over DV=256: partial sum over 64 cols, reduce across 4 lanes
  float ss = 0.f;
  #pragma unroll
  for (int vi = 0; vi < 64; ++vi) ss += o[vi]*o[vi];
  ss += __shfl_xor(ss, 1);
  ss += __shfl_xor(ss, 2);
  float inv = rsqrtf(ss * (1.0f/DV) + 1e-6f);
  const size_t gbase = ((size_t)(b*TDIM + nc*CHUNKC + c))*VD + h*DV + v0;
  for (int vi = 0; vi < 64; ++vi) {
    float gv = gbuf[gbase + vi];
    float sig = 1.f / (1.f + expf(-gv));
    float val = o[vi] * inv * gnw[v0 + vi];
    obuf[gbase + vi] = val * (gv * sig);
  }
}

extern "C" void kernel_launch(void* const* d_in, const int* in_sizes, int n_in,
                              void* d_out, int out_size, void* d_ws, size_t ws_size,
                              hipStream_t stream) {
  const float* x    = (const float*)d_in[0];
  const float* Wq   = (const float*)d_in[1];
  const float* Wk   = (const float*)d_in[2];
  const float* Wv   = (const float*)d_in[3];
  const float* Wg   = (const float*)d_in[4];
  const float* Wgk1 = (const float*)d_in[5];
  const float* Wgk2 = (const float*)d_in[6];
  const float* bgk2 = (const float*)d_in[7];
  const float* gnw  = (const float*)d_in[8];
  const float* Wo   = (const float*)d_in[9];
  float* out = (float*)d_out;

  float* ws  = (float*)d_ws;
  float* qb  = ws;                                   // 4096*512
  float* kb  = qb  + (size_t)MTOT*KD;                // 4096*512
  float* vb  = kb  + (size_t)MTOT*KD;                // 4096*1024
  float* gb  = vb  + (size_t)MTOT*VD;                // 4096*1024
  float* Gb  = gb  + (size_t)MTOT*VD;                // 4096*512 (gk then cumsum in place)
  float* xlr = Gb  + (size_t)MTOT*KD;                // 4096*16
  float* Sp  = xlr + (size_t)MTOT*16;                // 32*2*4*128*256
  float* ob  = Sp  + (size_t)NC*BDIM*HH*DK*DV;       // 4096*1024

  dim3 tb(16,16);
  gemm64<<<dim3(KD/64, MTOT/64), tb, 0, stream>>>(x, Wq, qb, MTOT, KD, DDIM);
  gemm64<<<dim3(KD/64, MTOT/64), tb, 0, stream>>>(x, Wk, kb, MTOT, KD, DDIM);
  gemm64<<<dim3(VD/64, MTOT/64), tb, 0, stream>>>(x, Wv, vb, MTOT, VD, DDIM);
  gemm64<<<dim3(VD/64, MTOT/64), tb, 0, stream>>>(x, Wg, gb, MTOT, VD, DDIM);
  lowrank_kernel<<<MTOT*16/256, 256, 0, stream>>>(x, Wgk1, xlr);
  gk_kernel<<<MTOT*KD/256, 256, 0, stream>>>(xlr, Wgk2, bgk2, Gb);
  cumsum_kernel<<<BDIM*NC*KD/256, 256, 0, stream>>>(Gb);
  scan_kernel<<<32, 256, 0, stream>>>(kb, vb, Gb, Sp);
  out_kernel<<<NC*BDIM*HH, 256, 0, stream>>>(qb, kb, vb, Gb, Sp, gb, gnw, ob);
  gemm64<<<dim3(DDIM/64, MTOT/64), tb, 0, stream>>>(ob, Wo, out, MTOT, DDIM, DDIM);
}

// Round 3
// 1235.488 us; speedup vs baseline: 1.5568x; 1.5568x over previous
//
#include <hip/hip_runtime.h>
#include <hip/hip_bf16.h>

#define BDIM 2
#define TDIM 2048
#define DDIM 1024
#define HH 4
#define KD 512
#define VD 1024
#define DK 128
#define DV 256
#define NC 32
#define CHUNKC 64
#define MTOT (BDIM*TDIM)   // 4096

// ---------------- generic tiled GEMM: C[M,N] = A[M,K] @ B[K,N] (all fp32) ----------------
__global__ __launch_bounds__(256) void gemm64(const float* __restrict__ A,
                                              const float* __restrict__ Bw,
                                              float* __restrict__ C,
                                              int M, int N, int K) {
  __shared__ float As[64][17];
  __shared__ float Bs[16][65];
  const int tx = threadIdx.x, ty = threadIdx.y;
  const int tid = ty*16 + tx;
  const int row0 = blockIdx.y*64, col0 = blockIdx.x*64;
  float acc[4][4] = {};
  for (int k0 = 0; k0 < K; k0 += 16) {
    #pragma unroll
    for (int i = 0; i < 4; ++i) {
      int idx = tid + 256*i;
      int r = idx >> 4, cc = idx & 15;
      As[r][cc] = A[(size_t)(row0+r)*K + k0 + cc];
    }
    #pragma unroll
    for (int i = 0; i < 4; ++i) {
      int idx = tid + 256*i;
      int r = idx >> 6, cc = idx & 63;
      Bs[r][cc] = Bw[(size_t)(k0+r)*N + col0 + cc];
    }
    __syncthreads();
    #pragma unroll
    for (int kk = 0; kk < 16; ++kk) {
      float a[4], bb[4];
      #pragma unroll
      for (int i = 0; i < 4; ++i) a[i] = As[ty*4+i][kk];
      #pragma unroll
      for (int j = 0; j < 4; ++j) bb[j] = Bs[kk][tx*4+j];
      #pragma unroll
      for (int i = 0; i < 4; ++i)
        #pragma unroll
        for (int j = 0; j < 4; ++j) acc[i][j] += a[i]*bb[j];
    }
    __syncthreads();
  }
  #pragma unroll
  for (int i = 0; i < 4; ++i)
    #pragma unroll
    for (int j = 0; j < 4; ++j)
      C[(size_t)(row0+ty*4+i)*N + col0 + tx*4 + j] = acc[i][j];
}

// ---------------- low-rank: xlr[M,16] = x[M,1024] @ Wgk1[1024,16] ----------------
__global__ void lowrank_kernel(const float* __restrict__ x, const float* __restrict__ W1,
                               float* __restrict__ xlr) {
  int t = blockIdx.x*256 + threadIdx.x;   // MTOT*16 threads
  int m = t >> 4, j = t & 15;
  float s = 0.f;
  for (int kk = 0; kk < DDIM; ++kk)
    s += x[(size_t)m*DDIM + kk] * W1[kk*16 + j];
  xlr[t] = s;
}

// ---------------- gk = log_sigmoid(xlr@Wgk2 + b)/16 ----------------
__global__ void gk_kernel(const float* __restrict__ xlr, const float* __restrict__ W2,
                          const float* __restrict__ bias, float* __restrict__ G) {
  int t = blockIdx.x*256 + threadIdx.x;  // MTOT*KD threads
  int m = t >> 9, n = t & 511;
  float s = bias[n];
  #pragma unroll
  for (int r = 0; r < 16; ++r) s += xlr[m*16 + r] * W2[r*KD + n];
  // log_sigmoid(s) = min(s,0) - log1p(exp(-|s|))
  float ls = fminf(s, 0.f) - log1pf(expf(-fabsf(s)));
  G[t] = ls * (1.0f/16.0f);
}

// ---------------- in-chunk cumsum (in place) ----------------
__global__ void cumsum_kernel(float* __restrict__ G) {
  int t = blockIdx.x*256 + threadIdx.x;  // BDIM*NC*KD = 32768 threads
  int col = t & 511;
  int bn = t >> 9;                        // b*NC + nc
  int nc = bn & 31, b = bn >> 5;
  size_t base = ((size_t)(b*TDIM + nc*CHUNKC))*KD + col;
  float acc = 0.f;
  for (int c = 0; c < CHUNKC; ++c) {
    acc += G[base + (size_t)c*KD];
    G[base + (size_t)c*KD] = acc;
  }
}

// ---------------- per-chunk state increment: U_nc = kbar^T @ v (fully parallel) ----
// grid: 1024 blocks = ((nc*8 + bh)*4 + vs); writes U into the Sprev slot for chunk nc
// and decay[nc][bh][k] (vs==0 only).
__global__ __launch_bounds__(256) void state_chunk_kernel(const float* __restrict__ kbuf,
                                                          const float* __restrict__ vbuf,
                                                          const float* __restrict__ G,
                                                          float* __restrict__ Sprev,
                                                          float* __restrict__ dec) {
  const int vs = blockIdx.x & 3;
  const int bh = (blockIdx.x >> 2) & 7;   // b*H + h
  const int nc = blockIdx.x >> 5;
  const int b = bh >> 2, h = bh & 3;
  const int t = threadIdx.x;
  __shared__ float kbar[CHUNKC][DK];
  __shared__ float glast[DK];
  const size_t rowbase = ((size_t)(b*TDIM + nc*CHUNKC))*KD + h*DK;
  if (t < DK) {
    float gl = G[rowbase + (size_t)63*KD + t];
    glast[t] = gl;
    if (vs == 0) dec[((size_t)nc*8 + bh)*DK + t] = expf(gl);
  }
  __syncthreads();
  #pragma unroll
  for (int i = 0; i < 32; ++i) {
    int idx = t + 256*i;
    int c = idx >> 7, kk = idx & 127;
    size_t off = rowbase + (size_t)c*KD + kk;
    kbar[c][kk] = kbuf[off] * expf(glast[kk] - G[off]);
  }
  __syncthreads();
  const int vc = t & 63;
  const int kr0 = (t >> 6) * 32;
  const int vcol = h*DV + vs*64 + vc;
  float acc[32];
  #pragma unroll
  for (int i = 0; i < 32; ++i) acc[i] = 0.f;
  for (int c = 0; c < CHUNKC; ++c) {
    float vv = vbuf[((size_t)(b*TDIM + nc*CHUNKC + c))*VD + vcol];
    #pragma unroll
    for (int i = 0; i < 32; ++i)
      acc[i] += kbar[c][kr0+i] * vv;
  }
  float* up = Sprev + ((size_t)nc*8 + bh)*((size_t)DK*DV);
  #pragma unroll
  for (int i = 0; i < 32; ++i)
    up[(size_t)(kr0+i)*DV + vs*64 + vc] = acc[i];
}

// ---------------- elementwise scan over chunks, in place on Sprev ----------------
// 262144 threads, each owns one (bh,k,v) strip: tmp=buf[nc]; buf[nc]=S; S=S*decay+tmp
__global__ __launch_bounds__(256) void state_scan_kernel(float* __restrict__ Sprev,
                                                         const float* __restrict__ dec) {
  const int e = blockIdx.x*256 + threadIdx.x;   // 0 .. 8*128*256-1
  const int k = (e >> 8) & 127;
  const int bh = e >> 15;
  const size_t stride = (size_t)8*DK*DV;        // one chunk of states
  float S = 0.f;
  for (int nc = 0; nc < NC; ++nc) {
    float u = Sprev[(size_t)nc*stride + e];
    Sprev[(size_t)nc*stride + e] = S;
    S = S * dec[((size_t)nc*8 + bh)*DK + k] + u;
  }
}

// ---------------- per-chunk output: o_inter + tril(A)@v, RMSNorm, silu gate ----------------
// grid: 256 blocks = nc*8 + b*4 + h
// LDS: qg 32KB + union(kg 32KB | A 16KB) = 64KB exactly.
__global__ __launch_bounds__(256) void out_kernel(const float* __restrict__ qbuf,
                                                  const float* __restrict__ kbuf,
                                                  const float* __restrict__ vbuf,
                                                  const float* __restrict__ G,
                                                  const float* __restrict__ Sprev,
                                                  const float* __restrict__ gbuf,
                                                  const float* __restrict__ gnw,
                                                  float* __restrict__ obuf) {
  const int blk = blockIdx.x;
  const int h = blk & 3, b = (blk >> 2) & 1, nc = blk >> 3;
  const int t = threadIdx.x;
  __shared__ float qg[CHUNKC][DK];
  __shared__ union { float kg[CHUNKC][DK]; float A[CHUNKC][CHUNKC]; } u;
  const float scale = 0.088388347648318447f;  // 128^-0.5
  const size_t rowbase = ((size_t)(b*TDIM + nc*CHUNKC))*KD + h*DK;
  // stage qg (plain) and kg (XOR-swizzled column) as fp32
  for (int i = 0; i < 32; ++i) {
    int idx = t + 256*i;
    int c = idx >> 7, kk = idx & 127;
    size_t off = rowbase + (size_t)c*KD + kk;
    float g = G[off];
    qg[c][kk] = qbuf[off] * expf(g) * scale;
    u.kg[c][kk ^ (c & 31)] = kbuf[off] * expf(-g);
  }
  __syncthreads();
  // A = tril(qg @ kg^T) into registers (16 entries/thread), then overwrite kg's LDS
  float areg[16];
  #pragma unroll
  for (int i = 0; i < 16; ++i) {
    int idx = t + 256*i;
    int c = idx >> 6, j = idx & 63;
    float s = 0.f;
    if (j <= c) {
      int sw = j & 31;
      #pragma unroll 8
      for (int kk = 0; kk < DK; ++kk)
        s += qg[c][kk] * u.kg[j][kk ^ sw];
    }
    areg[i] = s;
  }
  __syncthreads();
  #pragma unroll
  for (int i = 0; i < 16; ++i) {
    int idx = t + 256*i;
    int c = idx >> 6, j = idx & 63;
    u.A[c][j] = areg[i];
  }
  __syncthreads();
  const int c = t >> 2, vb = t & 3;
  const int v0 = vb*64;
  float o[64];
  #pragma unroll
  for (int vi = 0; vi < 64; ++vi) o[vi] = 0.f;
  const float* Sp = Sprev + (size_t)blk*((size_t)DK*DV);
  for (int kk = 0; kk < DK; ++kk) {
    float qv = qg[c][kk];
    const float* srow = Sp + (size_t)kk*DV + v0;
    #pragma unroll
    for (int vi = 0; vi < 64; ++vi) o[vi] += qv * srow[vi];
  }
  for (int j = 0; j <= c; ++j) {
    float a = u.A[c][j];
    const float* vrow = vbuf + ((size_t)(b*TDIM + nc*CHUNKC + j))*VD + h*DV + v0;
    #pragma unroll
    for (int vi = 0; vi < 64; ++vi) o[vi] += a * vrow[vi];
  }
  // RMSNorm over DV=256: partial sum over 64 cols, reduce across 4 lanes
  float ss = 0.f;
  #pragma unroll
  for (int vi = 0; vi < 64; ++vi) ss += o[vi]*o[vi];
  ss += __shfl_xor(ss, 1);
  ss += __shfl_xor(ss, 2);
  float inv = rsqrtf(ss * (1.0f/DV) + 1e-6f);
  const size_t gbase = ((size_t)(b*TDIM + nc*CHUNKC + c))*VD + h*DV + v0;
  for (int vi = 0; vi < 64; ++vi) {
    float gv = gbuf[gbase + vi];
    float sig = 1.f / (1.f + expf(-gv));
    float val = o[vi] * inv * gnw[v0 + vi];
    obuf[gbase + vi] = val * (gv * sig);
  }
}

extern "C" void kernel_launch(void* const* d_in, const int* in_sizes, int n_in,
                              void* d_out, int out_size, void* d_ws, size_t ws_size,
                              hipStream_t stream) {
  const float* x    = (const float*)d_in[0];
  const float* Wq   = (const float*)d_in[1];
  const float* Wk   = (const float*)d_in[2];
  const float* Wv   = (const float*)d_in[3];
  const float* Wg   = (const float*)d_in[4];
  const float* Wgk1 = (const float*)d_in[5];
  const float* Wgk2 = (const float*)d_in[6];
  const float* bgk2 = (const float*)d_in[7];
  const float* gnw  = (const float*)d_in[8];
  const float* Wo   = (const float*)d_in[9];
  float* out = (float*)d_out;

  float* ws  = (float*)d_ws;
  float* qb  = ws;                                   // 4096*512
  float* kb  = qb  + (size_t)MTOT*KD;                // 4096*512
  float* vb  = kb  + (size_t)MTOT*KD;                // 4096*1024
  float* gb  = vb  + (size_t)MTOT*VD;                // 4096*1024
  float* Gb  = gb  + (size_t)MTOT*VD;                // 4096*512 (gk then cumsum in place)
  float* xlr = Gb  + (size_t)MTOT*KD;                // 4096*16
  float* Sp  = xlr + (size_t)MTOT*16;                // 32*8*128*256 (U then S_prev in place)
  float* ob  = Sp  + (size_t)NC*BDIM*HH*DK*DV;       // 4096*1024
  float* dec = ob  + (size_t)MTOT*VD;                // 32*8*128

  dim3 tb(16,16);
  gemm64<<<dim3(KD/64, MTOT/64), tb, 0, stream>>>(x, Wq, qb, MTOT, KD, DDIM);
  gemm64<<<dim3(KD/64, MTOT/64), tb, 0, stream>>>(x, Wk, kb, MTOT, KD, DDIM);
  gemm64<<<dim3(VD/64, MTOT/64), tb, 0, stream>>>(x, Wv, vb, MTOT, VD, DDIM);
  gemm64<<<dim3(VD/64, MTOT/64), tb, 0, stream>>>(x, Wg, gb, MTOT, VD, DDIM);
  lowrank_kernel<<<MTOT*16/256, 256, 0, stream>>>(x, Wgk1, xlr);
  gk_kernel<<<MTOT*KD/256, 256, 0, stream>>>(xlr, Wgk2, bgk2, Gb);
  cumsum_kernel<<<BDIM*NC*KD/256, 256, 0, stream>>>(Gb);
  state_chunk_kernel<<<NC*BDIM*HH*4, 256, 0, stream>>>(kb, vb, Gb, Sp, dec);
  state_scan_kernel<<<BDIM*HH*DK*DV/256, 256, 0, stream>>>(Sp, dec);
  out_kernel<<<NC*BDIM*HH, 256, 0, stream>>>(qb, kb, vb, Gb, Sp, gb, gnw, ob);
  gemm64<<<dim3(DDIM/64, MTOT/64), tb, 0, stream>>>(ob, Wo, out, MTOT, DDIM, DDIM);
}

// Round 4
// 615.228 us; speedup vs baseline: 3.1263x; 2.0082x over previous
//
#include <hip/hip_runtime.h>
#include <hip/hip_bf16.h>

#define BDIM 2
#define TDIM 2048
#define DDIM 1024
#define HH 4
#define KD 512
#define VD 1024
#define DK 128
#define DV 256
#define NC 32
#define CHUNKC 64
#define MTOT (BDIM*TDIM)   // 4096
#define QKN 1024           // combined q|k row length
#define VGN 2048           // combined v|g row length

typedef __bf16 bf16x8 __attribute__((ext_vector_type(8)));
typedef float  f32x4  __attribute__((ext_vector_type(4)));
typedef __hip_bfloat16 hbf;

__device__ __forceinline__ void async_copy16(const void* g, void* l) {
  __builtin_amdgcn_global_load_lds(
      (const __attribute__((address_space(1))) void*)g,
      (__attribute__((address_space(3))) void*)l, 16, 0, 0);
}

// ---------------- cast x (fp32 -> bf16), 4 elems/thread ----------------
__global__ void cast_bf16_kernel(const float* __restrict__ src, hbf* __restrict__ dst) {
  int t = blockIdx.x*256 + threadIdx.x;
  float4 v = ((const float4*)src)[t];
  union { hbf h[4]; uint2 u; } o;
  o.h[0] = __float2bfloat16(v.x); o.h[1] = __float2bfloat16(v.y);
  o.h[2] = __float2bfloat16(v.z); o.h[3] = __float2bfloat16(v.w);
  ((uint2*)dst)[t] = o.u;
}

// ---------------- transpose + cast: Wt[n][k] = W[k][n] ----------------
// grid: (N/32, K/32), 256 threads
__global__ void transpose_cast_kernel(const float* __restrict__ W, hbf* __restrict__ Wt,
                                      int K, int N) {
  __shared__ float tile[32][33];
  const int bx = blockIdx.x, by = blockIdx.y;
  const int tx = threadIdx.x & 31, ty = threadIdx.x >> 5;  // ty 0..7
  #pragma unroll
  for (int r = ty; r < 32; r += 8)
    tile[r][tx] = W[(size_t)(by*32 + r)*N + bx*32 + tx];
  __syncthreads();
  #pragma unroll
  for (int r = ty; r < 32; r += 8)
    Wt[(size_t)(bx*32 + r)*K + by*32 + tx] = __float2bfloat16(tile[tx][r]);
}

// ---------------- MFMA GEMM: C[M,N] (fp32) = A[M,K] (bf16) @ Bt[N,K]^T (bf16) ----
// 128x128 tile, BK=32, 256 threads (4 waves, 2x2 wave grid), global_load_lds staging.
__global__ __launch_bounds__(256) void gemm_bt(const hbf* __restrict__ A,
                                               const hbf* __restrict__ Bt,
                                               float* __restrict__ C,
                                               int M, int N, int K) {
  __shared__ hbf As[128][32];
  __shared__ hbf Bs[128][32];
  const int t = threadIdx.x;
  const int w = t >> 6, l = t & 63;
  const int lr = l >> 2, lc = (l & 3)*8;     // staging: row-in-16, col (bf16)
  const int lane16 = l & 15, quad = l >> 4;  // mfma fragment coords
  const int row0 = blockIdx.y*128, col0 = blockIdx.x*128;
  const int mb = (w >> 1)*64, nb = (w & 1)*64;

  const hbf* ga = A  + (size_t)(row0 + w*32 + lr)*K + lc;
  const hbf* gb = Bt + (size_t)(col0 + w*32 + lr)*K + lc;
  hbf* la0 = &As[w*32][0];      hbf* la1 = &As[w*32 + 16][0];
  hbf* lb0 = &Bs[w*32][0];      hbf* lb1 = &Bs[w*32 + 16][0];
  const size_t rstep = (size_t)16*K;

  f32x4 acc[4][4] = {};
  for (int k0 = 0; k0 < K; k0 += 32) {
    async_copy16(ga,         la0);
    async_copy16(ga + rstep, la1);
    async_copy16(gb,         lb0);
    async_copy16(gb + rstep, lb1);
    ga += 32; gb += 32;
    __syncthreads();   // compiler drains vmcnt before barrier
    bf16x8 af[4], bfr[4];
    #pragma unroll
    for (int i = 0; i < 4; ++i)
      af[i] = *(const bf16x8*)&As[mb + i*16 + lane16][quad*8];
    #pragma unroll
    for (int j = 0; j < 4; ++j)
      bfr[j] = *(const bf16x8*)&Bs[nb + j*16 + lane16][quad*8];
    #pragma unroll
    for (int i = 0; i < 4; ++i)
      #pragma unroll
      for (int j = 0; j < 4; ++j)
        acc[i][j] = __builtin_amdgcn_mfma_f32_16x16x32_bf16(af[i], bfr[j], acc[i][j], 0, 0, 0);
    __syncthreads();   // all reads done before next staging overwrites
  }
  #pragma unroll
  for (int i = 0; i < 4; ++i) {
    #pragma unroll
    for (int j = 0; j < 4; ++j) {
      #pragma unroll
      for (int r = 0; r < 4; ++r) {
        int m = row0 + mb + i*16 + quad*4 + r;
        int n = col0 + nb + j*16 + lane16;
        C[(size_t)m*N + n] = acc[i][j][r];
      }
    }
  }
}

// ---------------- low-rank: xlr[M,16] = x[M,1024] @ Wgk1[1024,16] ----------------
__global__ void lowrank_kernel(const float* __restrict__ x, const float* __restrict__ W1,
                               float* __restrict__ xlr) {
  int t = blockIdx.x*256 + threadIdx.x;   // MTOT*16 threads
  int m = t >> 4, j = t & 15;
  float s = 0.f;
  for (int kk = 0; kk < DDIM; ++kk)
    s += x[(size_t)m*DDIM + kk] * W1[kk*16 + j];
  xlr[t] = s;
}

// ---------------- gk = log_sigmoid(xlr@Wgk2 + b)/16 ----------------
__global__ void gk_kernel(const float* __restrict__ xlr, const float* __restrict__ W2,
                          const float* __restrict__ bias, float* __restrict__ G) {
  int t = blockIdx.x*256 + threadIdx.x;  // MTOT*KD threads
  int m = t >> 9, n = t & 511;
  float s = bias[n];
  #pragma unroll
  for (int r = 0; r < 16; ++r) s += xlr[m*16 + r] * W2[r*KD + n];
  float ls = fminf(s, 0.f) - log1pf(expf(-fabsf(s)));
  G[t] = ls * (1.0f/16.0f);
}

// ---------------- in-chunk cumsum (in place) ----------------
__global__ void cumsum_kernel(float* __restrict__ G) {
  int t = blockIdx.x*256 + threadIdx.x;  // BDIM*NC*KD = 32768 threads
  int col = t & 511;
  int bn = t >> 9;
  int nc = bn & 31, b = bn >> 5;
  size_t base = ((size_t)(b*TDIM + nc*CHUNKC))*KD + col;
  float acc = 0.f;
  for (int c = 0; c < CHUNKC; ++c) {
    acc += G[base + (size_t)c*KD];
    G[base + (size_t)c*KD] = acc;
  }
}

// ---------------- per-chunk state increment: U_nc = kbar^T @ v ----------------
// grid: 1024 blocks = ((nc*8 + bh)*4 + vs)
__global__ __launch_bounds__(256) void state_chunk_kernel(const float* __restrict__ qkb,
                                                          const float* __restrict__ vgb,
                                                          const float* __restrict__ G,
                                                          float* __restrict__ Sprev,
                                                          float* __restrict__ dec) {
  const int vs = blockIdx.x & 3;
  const int bh = (blockIdx.x >> 2) & 7;
  const int nc = blockIdx.x >> 5;
  const int b = bh >> 2, h = bh & 3;
  const int t = threadIdx.x;
  __shared__ float kbar[CHUNKC][DK];
  __shared__ float glast[DK];
  const size_t grow = ((size_t)(b*TDIM + nc*CHUNKC))*KD + h*DK;
  const size_t krow = ((size_t)(b*TDIM + nc*CHUNKC))*QKN + 512 + h*DK;
  if (t < DK) {
    float gl = G[grow + (size_t)63*KD + t];
    glast[t] = gl;
    if (vs == 0) dec[((size_t)nc*8 + bh)*DK + t] = expf(gl);
  }
  __syncthreads();
  #pragma unroll
  for (int i = 0; i < 32; ++i) {
    int idx = t + 256*i;
    int c = idx >> 7, kk = idx & 127;
    kbar[c][kk] = qkb[krow + (size_t)c*QKN + kk] * expf(glast[kk] - G[grow + (size_t)c*KD + kk]);
  }
  __syncthreads();
  const int vc = t & 63;
  const int kr0 = (t >> 6) * 32;
  const size_t vcol = ((size_t)(b*TDIM + nc*CHUNKC))*VGN + h*DV + vs*64 + vc;
  float acc[32];
  #pragma unroll
  for (int i = 0; i < 32; ++i) acc[i] = 0.f;
  for (int c = 0; c < CHUNKC; ++c) {
    float vv = vgb[vcol + (size_t)c*VGN];
    #pragma unroll
    for (int i = 0; i < 32; ++i)
      acc[i] += kbar[c][kr0+i] * vv;
  }
  float* up = Sprev + ((size_t)nc*8 + bh)*((size_t)DK*DV);
  #pragma unroll
  for (int i = 0; i < 32; ++i)
    up[(size_t)(kr0+i)*DV + vs*64 + vc] = acc[i];
}

// ---------------- elementwise scan over chunks, in place on Sprev ----------------
__global__ __launch_bounds__(256) void state_scan_kernel(float* __restrict__ Sprev,
                                                         const float* __restrict__ dec) {
  const int e = blockIdx.x*256 + threadIdx.x;   // 0 .. 8*128*256-1
  const int k = (e >> 8) & 127;
  const int bh = e >> 15;
  const size_t stride = (size_t)8*DK*DV;
  float S = 0.f;
  for (int nc = 0; nc < NC; ++nc) {
    float u = Sprev[(size_t)nc*stride + e];
    Sprev[(size_t)nc*stride + e] = S;
    S = S * dec[((size_t)nc*8 + bh)*DK + k] + u;
  }
}

// ---------------- per-chunk output: o_inter + tril(A)@v, RMSNorm, silu gate ----------------
// grid: 256 blocks = nc*8 + b*4 + h; writes bf16 o.
__global__ __launch_bounds__(256) void out_kernel(const float* __restrict__ qkb,
                                                  const float* __restrict__ vgb,
                                                  const float* __restrict__ G,
                                                  const float* __restrict__ Sprev,
                                                  const float* __restrict__ gnw,
                                                  hbf* __restrict__ obf) {
  const int blk = blockIdx.x;
  const int h = blk & 3, b = (blk >> 2) & 1, nc = blk >> 3;
  const int t = threadIdx.x;
  __shared__ float qg[CHUNKC][DK];
  __shared__ union { float kg[CHUNKC][DK]; float A[CHUNKC][CHUNKC]; } u;
  const float scale = 0.088388347648318447f;  // 128^-0.5
  const size_t grow = ((size_t)(b*TDIM + nc*CHUNKC))*KD + h*DK;
  const size_t qrow = ((size_t)(b*TDIM + nc*CHUNKC))*QKN + h*DK;
  for (int i = 0; i < 32; ++i) {
    int idx = t + 256*i;
    int c = idx >> 7, kk = idx & 127;
    float g = G[grow + (size_t)c*KD + kk];
    qg[c][kk] = qkb[qrow + (size_t)c*QKN + kk] * expf(g) * scale;
    u.kg[c][kk ^ (c & 31)] = qkb[qrow + (size_t)c*QKN + 512 + kk] * expf(-g);
  }
  __syncthreads();
  float areg[16];
  #pragma unroll
  for (int i = 0; i < 16; ++i) {
    int idx = t + 256*i;
    int c = idx >> 6, j = idx & 63;
    float s = 0.f;
    if (j <= c) {
      int sw = j & 31;
      #pragma unroll 8
      for (int kk = 0; kk < DK; ++kk)
        s += qg[c][kk] * u.kg[j][kk ^ sw];
    }
    areg[i] = s;
  }
  __syncthreads();
  #pragma unroll
  for (int i = 0; i < 16; ++i) {
    int idx = t + 256*i;
    int c = idx >> 6, j = idx & 63;
    u.A[c][j] = areg[i];
  }
  __syncthreads();
  const int c = t >> 2, vb = t & 3;
  const int v0 = vb*64;
  float o[64];
  #pragma unroll
  for (int vi = 0; vi < 64; ++vi) o[vi] = 0.f;
  const float* Sp = Sprev + (size_t)blk*((size_t)DK*DV);
  for (int kk = 0; kk < DK; ++kk) {
    float qv = qg[c][kk];
    const float* srow = Sp + (size_t)kk*DV + v0;
    #pragma unroll
    for (int vi = 0; vi < 64; ++vi) o[vi] += qv * srow[vi];
  }
  for (int j = 0; j <= c; ++j) {
    float a = u.A[c][j];
    const float* vrow = vgb + ((size_t)(b*TDIM + nc*CHUNKC + j))*VGN + h*DV + v0;
    #pragma unroll
    for (int vi = 0; vi < 64; ++vi) o[vi] += a * vrow[vi];
  }
  float ss = 0.f;
  #pragma unroll
  for (int vi = 0; vi < 64; ++vi) ss += o[vi]*o[vi];
  ss += __shfl_xor(ss, 1);
  ss += __shfl_xor(ss, 2);
  float inv = rsqrtf(ss * (1.0f/DV) + 1e-6f);
  const size_t gbase = ((size_t)(b*TDIM + nc*CHUNKC + c))*VGN + 1024 + h*DV + v0;
  const size_t obase = ((size_t)(b*TDIM + nc*CHUNKC + c))*VD + h*DV + v0;
  for (int vi = 0; vi < 64; ++vi) {
    float gv = vgb[gbase + vi];
    float sig = 1.f / (1.f + expf(-gv));
    float val = o[vi] * inv * gnw[v0 + vi];
    obf[obase + vi] = __float2bfloat16(val * (gv * sig));
  }
}

extern "C" void kernel_launch(void* const* d_in, const int* in_sizes, int n_in,
                              void* d_out, int out_size, void* d_ws, size_t ws_size,
                              hipStream_t stream) {
  const float* x    = (const float*)d_in[0];
  const float* Wq   = (const float*)d_in[1];
  const float* Wk   = (const float*)d_in[2];
  const float* Wv   = (const float*)d_in[3];
  const float* Wg   = (const float*)d_in[4];
  const float* Wgk1 = (const float*)d_in[5];
  const float* Wgk2 = (const float*)d_in[6];
  const float* bgk2 = (const float*)d_in[7];
  const float* gnw  = (const float*)d_in[8];
  const float* Wo   = (const float*)d_in[9];
  float* out = (float*)d_out;

  float* ws  = (float*)d_ws;
  float* qkb = ws;                                   // 4096*1024 fp32 (q|k)
  float* vgb = qkb + (size_t)MTOT*QKN;               // 4096*2048 fp32 (v|g)
  float* Gb  = vgb + (size_t)MTOT*VGN;               // 4096*512
  float* xlr = Gb  + (size_t)MTOT*KD;                // 4096*16
  float* Sp  = xlr + (size_t)MTOT*16;                // 32*8*128*256
  float* dec = Sp  + (size_t)NC*BDIM*HH*DK*DV;       // 32*8*128
  float* bfr = dec + (size_t)NC*BDIM*HH*DK;          // bf16 region start
  hbf* xbf  = (hbf*)bfr;                             // 4096*1024
  hbf* wtqk = xbf  + (size_t)MTOT*DDIM;              // 1024*1024 (Wq^T | Wk^T)
  hbf* wtvg = wtqk + (size_t)QKN*DDIM;               // 2048*1024 (Wv^T | Wg^T)
  hbf* wto  = wtvg + (size_t)VGN*DDIM;               // 1024*1024
  hbf* obf  = wto  + (size_t)DDIM*DDIM;              // 4096*1024

  cast_bf16_kernel<<<MTOT*DDIM/4/256, 256, 0, stream>>>(x, xbf);
  transpose_cast_kernel<<<dim3(512/32, DDIM/32), 256, 0, stream>>>(Wq, wtqk, DDIM, 512);
  transpose_cast_kernel<<<dim3(512/32, DDIM/32), 256, 0, stream>>>(Wk, wtqk + (size_t)512*DDIM, DDIM, 512);
  transpose_cast_kernel<<<dim3(1024/32, DDIM/32), 256, 0, stream>>>(Wv, wtvg, DDIM, 1024);
  transpose_cast_kernel<<<dim3(1024/32, DDIM/32), 256, 0, stream>>>(Wg, wtvg + (size_t)1024*DDIM, DDIM, 1024);
  transpose_cast_kernel<<<dim3(1024/32, DDIM/32), 256, 0, stream>>>(Wo, wto, DDIM, 1024);

  gemm_bt<<<dim3(QKN/128, MTOT/128), 256, 0, stream>>>(xbf, wtqk, qkb, MTOT, QKN, DDIM);
  gemm_bt<<<dim3(VGN/128, MTOT/128), 256, 0, stream>>>(xbf, wtvg, vgb, MTOT, VGN, DDIM);

  lowrank_kernel<<<MTOT*16/256, 256, 0, stream>>>(x, Wgk1, xlr);
  gk_kernel<<<MTOT*KD/256, 256, 0, stream>>>(xlr, Wgk2, bgk2, Gb);
  cumsum_kernel<<<BDIM*NC*KD/256, 256, 0, stream>>>(Gb);
  state_chunk_kernel<<<NC*BDIM*HH*4, 256, 0, stream>>>(qkb, vgb, Gb, Sp, dec);
  state_scan_kernel<<<BDIM*HH*DK*DV/256, 256, 0, stream>>>(Sp, dec);
  out_kernel<<<NC*BDIM*HH, 256, 0, stream>>>(qkb, vgb, Gb, Sp, gnw, obf);
  gemm_bt<<<dim3(DDIM/128, MTOT/128), 256, 0, stream>>>(obf, wto, out, MTOT, DDIM, DDIM);
}

// Round 5
// 311.426 us; speedup vs baseline: 6.1761x; 1.9755x over previous
//
#include <hip/hip_runtime.h>
#include <hip/hip_bf16.h>

#define BDIM 2
#define TDIM 2048
#define DDIM 1024
#define HH 4
#define KD 512
#define VD 1024
#define DK 128
#define DV 256
#define NC 32
#define CHUNKC 64
#define MTOT (BDIM*TDIM)   // 4096
#define QKN 1024           // combined q|k row length
#define VGN 2048           // combined v|g row length
#define STRIDE_ST ((size_t)BDIM*HH*DK*DV)   // 262144 elems per chunk of states

typedef __bf16 bf16x8 __attribute__((ext_vector_type(8)));
typedef float  f32x4  __attribute__((ext_vector_type(4)));
typedef __hip_bfloat16 hbf;

__device__ __forceinline__ void async_copy16(const void* g, void* l) {
  __builtin_amdgcn_global_load_lds(
      (const __attribute__((address_space(1))) void*)g,
      (__attribute__((address_space(3))) void*)l, 16, 0, 0);
}

// ---------------- cast x (fp32 -> bf16), 4 elems/thread ----------------
__global__ void cast_bf16_kernel(const float* __restrict__ src, hbf* __restrict__ dst) {
  int t = blockIdx.x*256 + threadIdx.x;
  float4 v = ((const float4*)src)[t];
  union { hbf h[4]; uint2 u; } o;
  o.h[0] = __float2bfloat16(v.x); o.h[1] = __float2bfloat16(v.y);
  o.h[2] = __float2bfloat16(v.z); o.h[3] = __float2bfloat16(v.w);
  ((uint2*)dst)[t] = o.u;
}

// ---------------- transpose + cast: Wt[n][k] = W[k][n] ----------------
__global__ void transpose_cast_kernel(const float* __restrict__ W, hbf* __restrict__ Wt,
                                      int K, int N) {
  __shared__ float tile[32][33];
  const int bx = blockIdx.x, by = blockIdx.y;
  const int tx = threadIdx.x & 31, ty = threadIdx.x >> 5;
  #pragma unroll
  for (int r = ty; r < 32; r += 8)
    tile[r][tx] = W[(size_t)(by*32 + r)*N + bx*32 + tx];
  __syncthreads();
  #pragma unroll
  for (int r = ty; r < 32; r += 8)
    Wt[(size_t)(bx*32 + r)*K + by*32 + tx] = __float2bfloat16(tile[tx][r]);
}

// ---------------- MFMA GEMM: C[M,N] (fp32) = A[M,K] (bf16) @ Bt[N,K]^T (bf16) ----
__global__ __launch_bounds__(256) void gemm_bt(const hbf* __restrict__ A,
                                               const hbf* __restrict__ Bt,
                                               float* __restrict__ C,
                                               int M, int N, int K) {
  __shared__ hbf As[128][32];
  __shared__ hbf Bs[128][32];
  const int t = threadIdx.x;
  const int w = t >> 6, l = t & 63;
  const int lr = l >> 2, lc = (l & 3)*8;
  const int lane16 = l & 15, quad = l >> 4;
  const int row0 = blockIdx.y*128, col0 = blockIdx.x*128;
  const int mb = (w >> 1)*64, nb = (w & 1)*64;

  const hbf* ga = A  + (size_t)(row0 + w*32 + lr)*K + lc;
  const hbf* gb = Bt + (size_t)(col0 + w*32 + lr)*K + lc;
  hbf* la0 = &As[w*32][0];      hbf* la1 = &As[w*32 + 16][0];
  hbf* lb0 = &Bs[w*32][0];      hbf* lb1 = &Bs[w*32 + 16][0];
  const size_t rstep = (size_t)16*K;

  f32x4 acc[4][4] = {};
  for (int k0 = 0; k0 < K; k0 += 32) {
    async_copy16(ga,         la0);
    async_copy16(ga + rstep, la1);
    async_copy16(gb,         lb0);
    async_copy16(gb + rstep, lb1);
    ga += 32; gb += 32;
    __syncthreads();
    bf16x8 af[4], bfr[4];
    #pragma unroll
    for (int i = 0; i < 4; ++i)
      af[i] = *(const bf16x8*)&As[mb + i*16 + lane16][quad*8];
    #pragma unroll
    for (int j = 0; j < 4; ++j)
      bfr[j] = *(const bf16x8*)&Bs[nb + j*16 + lane16][quad*8];
    #pragma unroll
    for (int i = 0; i < 4; ++i)
      #pragma unroll
      for (int j = 0; j < 4; ++j)
        acc[i][j] = __builtin_amdgcn_mfma_f32_16x16x32_bf16(af[i], bfr[j], acc[i][j], 0, 0, 0);
    __syncthreads();
  }
  #pragma unroll
  for (int i = 0; i < 4; ++i)
    #pragma unroll
    for (int j = 0; j < 4; ++j)
      #pragma unroll
      for (int r = 0; r < 4; ++r) {
        int m = row0 + mb + i*16 + quad*4 + r;
        int n = col0 + nb + j*16 + lane16;
        C[(size_t)m*N + n] = acc[i][j][r];
      }
}

// ---------------- low-rank: xlr[M,16] = x[M,1024] @ Wgk1[1024,16] ----------------
__global__ void lowrank_kernel(const float* __restrict__ x, const float* __restrict__ W1,
                               float* __restrict__ xlr) {
  int t = blockIdx.x*256 + threadIdx.x;
  int m = t >> 4, j = t & 15;
  float s = 0.f;
  for (int kk = 0; kk < DDIM; ++kk)
    s += x[(size_t)m*DDIM + kk] * W1[kk*16 + j];
  xlr[t] = s;
}

// ---------------- gk = log_sigmoid(xlr@Wgk2 + b)/16 ----------------
__global__ void gk_kernel(const float* __restrict__ xlr, const float* __restrict__ W2,
                          const float* __restrict__ bias, float* __restrict__ G) {
  int t = blockIdx.x*256 + threadIdx.x;
  int m = t >> 9, n = t & 511;
  float s = bias[n];
  #pragma unroll
  for (int r = 0; r < 16; ++r) s += xlr[m*16 + r] * W2[r*KD + n];
  float ls = fminf(s, 0.f) - log1pf(expf(-fabsf(s)));
  G[t] = ls * (1.0f/16.0f);
}

// ---------------- in-chunk cumsum (in place) ----------------
__global__ void cumsum_kernel(float* __restrict__ G) {
  int t = blockIdx.x*256 + threadIdx.x;
  int col = t & 511;
  int bn = t >> 9;
  int nc = bn & 31, b = bn >> 5;
  size_t base = ((size_t)(b*TDIM + nc*CHUNKC))*KD + col;
  float acc = 0.f;
  for (int c = 0; c < CHUNKC; ++c) {
    acc += G[base + (size_t)c*KD];
    G[base + (size_t)c*KD] = acc;
  }
}

// ---------------- per-chunk state increment: U_nc = kbar^T @ v, stored [v][k] ----
// grid: 1024 blocks = ((nc*8 + bh)*4 + vs)
__global__ __launch_bounds__(256) void state_chunk_kernel(const float* __restrict__ qkb,
                                                          const float* __restrict__ vgb,
                                                          const float* __restrict__ G,
                                                          float* __restrict__ U,
                                                          float* __restrict__ dec) {
  const int vs = blockIdx.x & 3;
  const int bh = (blockIdx.x >> 2) & 7;
  const int nc = blockIdx.x >> 5;
  const int b = bh >> 2, h = bh & 3;
  const int t = threadIdx.x;
  __shared__ float kbar[CHUNKC][DK];
  __shared__ float glast[DK];
  const size_t grow = ((size_t)(b*TDIM + nc*CHUNKC))*KD + h*DK;
  const size_t krow = ((size_t)(b*TDIM + nc*CHUNKC))*QKN + 512 + h*DK;
  if (t < DK) {
    float gl = G[grow + (size_t)63*KD + t];
    glast[t] = gl;
    if (vs == 0) dec[((size_t)nc*8 + bh)*DK + t] = expf(gl);
  }
  __syncthreads();
  #pragma unroll
  for (int i = 0; i < 32; ++i) {
    int idx = t + 256*i;
    int c = idx >> 7, kk = idx & 127;
    kbar[c][kk] = qkb[krow + (size_t)c*QKN + kk] * expf(glast[kk] - G[grow + (size_t)c*KD + kk]);
  }
  __syncthreads();
  const int vc = t & 63;
  const int kr0 = (t >> 6) * 32;
  const size_t vcol = ((size_t)(b*TDIM + nc*CHUNKC))*VGN + h*DV + vs*64 + vc;
  float acc[32];
  #pragma unroll
  for (int i = 0; i < 32; ++i) acc[i] = 0.f;
  for (int c = 0; c < CHUNKC; ++c) {
    float vv = vgb[vcol + (size_t)c*VGN];
    #pragma unroll
    for (int i = 0; i < 32; ++i)
      acc[i] += kbar[c][kr0+i] * vv;
  }
  // write U transposed: [v][k], per-lane float4 along k
  float* up = U + ((size_t)nc*8 + bh)*((size_t)DK*DV) + (size_t)(vs*64 + vc)*DK + kr0;
  #pragma unroll
  for (int i4 = 0; i4 < 8; ++i4)
    ((float4*)up)[i4] = make_float4(acc[i4*4], acc[i4*4+1], acc[i4*4+2], acc[i4*4+3]);
}

// ---------------- elementwise scan over chunks: reads U fp32, writes S_prev bf16 ----
// e maps k-fastest over [bh][v][k]; both streams coalesced.
__global__ __launch_bounds__(256) void state_scan_kernel(const float* __restrict__ U,
                                                         const float* __restrict__ dec,
                                                         hbf* __restrict__ Spb) {
  const int e = blockIdx.x*256 + threadIdx.x;   // 0 .. 262143
  const int k = e & 127;
  const int bh = e >> 15;
  float S = 0.f;
  for (int nc = 0; nc < NC; ++nc) {
    float u = U[(size_t)nc*STRIDE_ST + e];
    Spb[(size_t)nc*STRIDE_ST + e] = __float2bfloat16(S);
    S = S * dec[((size_t)nc*8 + bh)*DK + k] + u;
  }
}

// ---------------- per-chunk output (MFMA): tril(qg kg^T), qg@S + A@v, RMSNorm, gate ----
// grid: 256 blocks = nc*8 + b*4 + h; 256 threads (4 waves).
__global__ __launch_bounds__(256) void out_kernel(const float* __restrict__ qkb,
                                                  const float* __restrict__ vgb,
                                                  const float* __restrict__ G,
                                                  const hbf* __restrict__ Spb,
                                                  const float* __restrict__ gnw,
                                                  hbf* __restrict__ obf) {
  const int blk = blockIdx.x;
  const int h = blk & 3, b = (blk >> 2) & 1, nc = blk >> 3;
  const int t = threadIdx.x;
  const int w = t >> 6, l = t & 63;
  const int lane16 = l & 15, quad = l >> 4;

  __shared__ __align__(16) unsigned char smem[64768];
  hbf (*qgs)[136] = (hbf(*)[136])(smem);                 // 17408 B
  hbf (*Ald)[72]  = (hbf(*)[72]) (smem + 17408);         //  9216 B
  hbf (*kgs)[136] = (hbf(*)[136])(smem + 26624);         // 17408 B (phase 1)
  hbf (*vT)[72]   = (hbf(*)[72]) (smem + 26624);         // 36864 B (phase 2, aliases kgs)
  float* ssum     = (float*)     (smem + 63488);         // 64*4
  float* invb     = (float*)     (smem + 64512);         // 64

  const float scale = 0.088388347648318447f;  // 128^-0.5
  const int bc = b*TDIM + nc*CHUNKC;          // first token of chunk
  const size_t growb = (size_t)bc*KD + h*DK;
  const size_t qrowb = (size_t)bc*QKN + h*DK;

  // ---- stage qg, kg (bf16) ----
  #pragma unroll
  for (int i = 0; i < 32; ++i) {
    int idx = t + 256*i;
    int c = idx >> 7, kk = idx & 127;
    float g = G[growb + (size_t)c*KD + kk];
    qgs[c][kk] = __float2bfloat16(qkb[qrowb + (size_t)c*QKN + kk] * expf(g) * scale);
    kgs[c][kk] = __float2bfloat16(qkb[qrowb + (size_t)c*QKN + 512 + kk] * expf(-g));
  }
  __syncthreads();

  // ---- phase 1: A = tril(qg @ kg^T), wave w does rows w*16..w*16+15 ----
  f32x4 acc1[4] = {};
  #pragma unroll
  for (int kc = 0; kc < 4; ++kc) {
    bf16x8 af = *(const bf16x8*)&qgs[w*16 + lane16][kc*32 + quad*8];
    #pragma unroll
    for (int j = 0; j < 4; ++j) {
      bf16x8 bf = *(const bf16x8*)&kgs[j*16 + lane16][kc*32 + quad*8];
      acc1[j] = __builtin_amdgcn_mfma_f32_16x16x32_bf16(af, bf, acc1[j], 0, 0, 0);
    }
  }
  __syncthreads();   // all kgs reads done before vT overwrites

  // ---- store masked A (bf16) + stage vT (bf16, [v][c]) ----
  #pragma unroll
  for (int j = 0; j < 4; ++j)
    #pragma unroll
    for (int r = 0; r < 4; ++r) {
      int cr = w*16 + quad*4 + r;
      int cc = j*16 + lane16;
      Ald[cr][cc] = __float2bfloat16(cc <= cr ? acc1[j][r] : 0.f);
    }
  #pragma unroll
  for (int i = 0; i < 64; ++i) {
    int e = t + 256*i;
    int c = e >> 8, col = e & 255;
    vT[col][c] = __float2bfloat16(vgb[(size_t)(bc + c)*VGN + h*DV + col]);
  }
  __syncthreads();

  // ---- phase 2: o = qg @ S_prev + A @ v ; wave w owns v-col strip w*64 ----
  const hbf* SpB = Spb + ((size_t)nc*8 + (b*HH + h))*((size_t)DK*DV);
  f32x4 acc[4][4] = {};
  #pragma unroll
  for (int kc = 0; kc < 4; ++kc) {
    bf16x8 af[4], bs[4];
    #pragma unroll
    for (int i = 0; i < 4; ++i)
      af[i] = *(const bf16x8*)&qgs[i*16 + lane16][kc*32 + quad*8];
    #pragma unroll
    for (int j = 0; j < 4; ++j) {
      int n = w*64 + j*16 + lane16;
      bs[j] = *(const bf16x8*)(SpB + (size_t)n*DK + kc*32 + quad*8);
    }
    #pragma unroll
    for (int i = 0; i < 4; ++i)
      #pragma unroll
      for (int j = 0; j < 4; ++j)
        acc[i][j] = __builtin_amdgcn_mfma_f32_16x16x32_bf16(af[i], bs[j], acc[i][j], 0, 0, 0);
  }
  #pragma unroll
  for (int kc = 0; kc < 2; ++kc) {
    bf16x8 aa[4], bv[4];
    #pragma unroll
    for (int i = 0; i < 4; ++i)
      aa[i] = *(const bf16x8*)&Ald[i*16 + lane16][kc*32 + quad*8];
    #pragma unroll
    for (int j = 0; j < 4; ++j)
      bv[j] = *(const bf16x8*)&vT[w*64 + j*16 + lane16][kc*32 + quad*8];
    #pragma unroll
    for (int i = 0; i < 4; ++i)
      #pragma unroll
      for (int j = 0; j < 4; ++j)
        acc[i][j] = __builtin_amdgcn_mfma_f32_16x16x32_bf16(aa[i], bv[j], acc[i][j], 0, 0, 0);
  }

  // ---- epilogue: RMSNorm over DV=256 + silu gate, write bf16 ----
  #pragma unroll
  for (int i = 0; i < 4; ++i)
    #pragma unroll
    for (int r = 0; r < 4; ++r) {
      float s = 0.f;
      #pragma unroll
      for (int j = 0; j < 4; ++j) s += acc[i][j][r]*acc[i][j][r];
      s += __shfl_xor(s, 1); s += __shfl_xor(s, 2);
      s += __shfl_xor(s, 4); s += __shfl_xor(s, 8);
      if (lane16 == 0) ssum[(i*16 + quad*4 + r)*4 + w] = s;
    }
  __syncthreads();
  if (t < 64) {
    float tot = ssum[t*4] + ssum[t*4+1] + ssum[t*4+2] + ssum[t*4+3];
    invb[t] = rsqrtf(tot * (1.0f/DV) + 1e-6f);
  }
  __syncthreads();
  float gnwv[4];
  #pragma unroll
  for (int j = 0; j < 4; ++j) gnwv[j] = gnw[w*64 + j*16 + lane16];
  #pragma unroll
  for (int i = 0; i < 4; ++i)
    #pragma unroll
    for (int r = 0; r < 4; ++r) {
      int m = i*16 + quad*4 + r;
      float inv = invb[m];
      size_t grow_ = (size_t)(bc + m)*VGN + 1024 + h*DV + w*64;
      size_t orow_ = (size_t)(bc + m)*VD + h*DV + w*64;
      #pragma unroll
      for (int j = 0; j < 4; ++j) {
        float gv = vgb[grow_ + j*16 + lane16];
        float sig = 1.f / (1.f + expf(-gv));
        float val = acc[i][j][r] * inv * gnwv[j];
        obf[orow_ + j*16 + lane16] = __float2bfloat16(val * (gv * sig));
      }
    }
}

extern "C" void kernel_launch(void* const* d_in, const int* in_sizes, int n_in,
                              void* d_out, int out_size, void* d_ws, size_t ws_size,
                              hipStream_t stream) {
  const float* x    = (const float*)d_in[0];
  const float* Wq   = (const float*)d_in[1];
  const float* Wk   = (const float*)d_in[2];
  const float* Wv   = (const float*)d_in[3];
  const float* Wg   = (const float*)d_in[4];
  const float* Wgk1 = (const float*)d_in[5];
  const float* Wgk2 = (const float*)d_in[6];
  const float* bgk2 = (const float*)d_in[7];
  const float* gnw  = (const float*)d_in[8];
  const float* Wo   = (const float*)d_in[9];
  float* out = (float*)d_out;

  float* ws  = (float*)d_ws;
  float* qkb = ws;                                   // 4096*1024 fp32 (q|k)
  float* vgb = qkb + (size_t)MTOT*QKN;               // 4096*2048 fp32 (v|g)
  float* Gb  = vgb + (size_t)MTOT*VGN;               // 4096*512
  float* xlr = Gb  + (size_t)MTOT*KD;                // 4096*16
  float* U   = xlr + (size_t)MTOT*16;                // 32*262144 fp32 (chunk increments, [v][k])
  float* dec = U   + (size_t)NC*STRIDE_ST;           // 32*8*128
  float* bfr = dec + (size_t)NC*BDIM*HH*DK;          // bf16 region start
  hbf* xbf  = (hbf*)bfr;                             // 4096*1024
  hbf* wtqk = xbf  + (size_t)MTOT*DDIM;              // 1024*1024
  hbf* wtvg = wtqk + (size_t)QKN*DDIM;               // 2048*1024
  hbf* wto  = wtvg + (size_t)VGN*DDIM;               // 1024*1024
  hbf* Spb  = wto  + (size_t)DDIM*DDIM;              // 32*262144 bf16 S_prev [v][k]
  hbf* obf  = (hbf*)U;                               // alias: U dead before out_kernel

  cast_bf16_kernel<<<MTOT*DDIM/4/256, 256, 0, stream>>>(x, xbf);
  transpose_cast_kernel<<<dim3(512/32, DDIM/32), 256, 0, stream>>>(Wq, wtqk, DDIM, 512);
  transpose_cast_kernel<<<dim3(512/32, DDIM/32), 256, 0, stream>>>(Wk, wtqk + (size_t)512*DDIM, DDIM, 512);
  transpose_cast_kernel<<<dim3(1024/32, DDIM/32), 256, 0, stream>>>(Wv, wtvg, DDIM, 1024);
  transpose_cast_kernel<<<dim3(1024/32, DDIM/32), 256, 0, stream>>>(Wg, wtvg + (size_t)1024*DDIM, DDIM, 1024);
  transpose_cast_kernel<<<dim3(1024/32, DDIM/32), 256, 0, stream>>>(Wo, wto, DDIM, 1024);

  gemm_bt<<<dim3(QKN/128, MTOT/128), 256, 0, stream>>>(xbf, wtqk, qkb, MTOT, QKN, DDIM);
  gemm_bt<<<dim3(VGN/128, MTOT/128), 256, 0, stream>>>(xbf, wtvg, vgb, MTOT, VGN, DDIM);

  lowrank_kernel<<<MTOT*16/256, 256, 0, stream>>>(x, Wgk1, xlr);
  gk_kernel<<<MTOT*KD/256, 256, 0, stream>>>(xlr, Wgk2, bgk2, Gb);
  cumsum_kernel<<<BDIM*NC*KD/256, 256, 0, stream>>>(Gb);
  state_chunk_kernel<<<NC*BDIM*HH*4, 256, 0, stream>>>(qkb, vgb, Gb, U, dec);
  state_scan_kernel<<<(int)(STRIDE_ST/256), 256, 0, stream>>>(U, dec, Spb);
  out_kernel<<<NC*BDIM*HH, 256, 0, stream>>>(qkb, vgb, Gb, Spb, gnw, obf);
  gemm_bt<<<dim3(DDIM/128, MTOT/128), 256, 0, stream>>>(obf, wto, out, MTOT, DDIM, DDIM);
}

// Round 6
// 262.780 us; speedup vs baseline: 7.3195x; 1.1851x over previous
//
#include <hip/hip_runtime.h>
#include <hip/hip_bf16.h>

#define BDIM 2
#define TDIM 2048
#define DDIM 1024
#define HH 4
#define KD 512
#define VD 1024
#define DK 128
#define DV 256
#define NC 32
#define CHUNKC 64
#define MTOT (BDIM*TDIM)   // 4096
#define QKG 1536           // combined q|k|gk row length
#define VGN 2048           // combined v|g row length
#define STRIDE_ST ((size_t)BDIM*HH*DK*DV)   // 262144 elems per chunk of states

typedef __bf16 bf16x8 __attribute__((ext_vector_type(8)));
typedef float  f32x4  __attribute__((ext_vector_type(4)));
typedef __hip_bfloat16 hbf;

__device__ __forceinline__ void async_copy16(const void* g, void* l) {
  __builtin_amdgcn_global_load_lds(
      (const __attribute__((address_space(1))) void*)g,
      (__attribute__((address_space(3))) void*)l, 16, 0, 0);
}

// ---------------- cast x (fp32 -> bf16), 4 elems/thread ----------------
__global__ void cast_bf16_kernel(const float* __restrict__ src, hbf* __restrict__ dst) {
  int t = blockIdx.x*256 + threadIdx.x;
  float4 v = ((const float4*)src)[t];
  union { hbf h[4]; uint2 u; } o;
  o.h[0] = __float2bfloat16(v.x); o.h[1] = __float2bfloat16(v.y);
  o.h[2] = __float2bfloat16(v.z); o.h[3] = __float2bfloat16(v.w);
  ((uint2*)dst)[t] = o.u;
}

// ---------------- transpose + cast: Wt[n][k] = W[k][n] ----------------
__global__ void transpose_cast_kernel(const float* __restrict__ W, hbf* __restrict__ Wt,
                                      int K, int N) {
  __shared__ float tile[32][33];
  const int bx = blockIdx.x, by = blockIdx.y;
  const int tx = threadIdx.x & 31, ty = threadIdx.x >> 5;
  #pragma unroll
  for (int r = ty; r < 32; r += 8)
    tile[r][tx] = W[(size_t)(by*32 + r)*N + bx*32 + tx];
  __syncthreads();
  #pragma unroll
  for (int r = ty; r < 32; r += 8)
    Wt[(size_t)(bx*32 + r)*K + by*32 + tx] = __float2bfloat16(tile[tx][r]);
}

// ---------------- Wc^T[n][k] = (Wgk1 @ Wgk2)^T, bf16 ----------------
__global__ void wcomp_kernel(const float* __restrict__ W1, const float* __restrict__ W2,
                             hbf* __restrict__ Wct) {
  int idx = blockIdx.x*256 + threadIdx.x;   // 512*1024 threads
  int k = idx & 1023, n = idx >> 10;
  float s = 0.f;
  #pragma unroll
  for (int r = 0; r < 16; ++r) s += W1[k*16 + r] * W2[r*KD + n];
  Wct[(size_t)n*DDIM + k] = __float2bfloat16(s);
}

// ---------------- MFMA GEMM: C[M,N] (fp32) = A[M,K] (bf16) @ Bt[N,K]^T (bf16) ----
__global__ __launch_bounds__(256) void gemm_bt(const hbf* __restrict__ A,
                                               const hbf* __restrict__ Bt,
                                               float* __restrict__ C,
                                               int M, int N, int K) {
  __shared__ hbf As[128][32];
  __shared__ hbf Bs[128][32];
  const int t = threadIdx.x;
  const int w = t >> 6, l = t & 63;
  const int lr = l >> 2, lc = (l & 3)*8;
  const int lane16 = l & 15, quad = l >> 4;
  const int row0 = blockIdx.y*128, col0 = blockIdx.x*128;
  const int mb = (w >> 1)*64, nb = (w & 1)*64;

  const hbf* ga = A  + (size_t)(row0 + w*32 + lr)*K + lc;
  const hbf* gb = Bt + (size_t)(col0 + w*32 + lr)*K + lc;
  hbf* la0 = &As[w*32][0];      hbf* la1 = &As[w*32 + 16][0];
  hbf* lb0 = &Bs[w*32][0];      hbf* lb1 = &Bs[w*32 + 16][0];
  const size_t rstep = (size_t)16*K;

  f32x4 acc[4][4] = {};
  for (int k0 = 0; k0 < K; k0 += 32) {
    async_copy16(ga,         la0);
    async_copy16(ga + rstep, la1);
    async_copy16(gb,         lb0);
    async_copy16(gb + rstep, lb1);
    ga += 32; gb += 32;
    __syncthreads();
    bf16x8 af[4], bfr[4];
    #pragma unroll
    for (int i = 0; i < 4; ++i)
      af[i] = *(const bf16x8*)&As[mb + i*16 + lane16][quad*8];
    #pragma unroll
    for (int j = 0; j < 4; ++j)
      bfr[j] = *(const bf16x8*)&Bs[nb + j*16 + lane16][quad*8];
    #pragma unroll
    for (int i = 0; i < 4; ++i)
      #pragma unroll
      for (int j = 0; j < 4; ++j)
        acc[i][j] = __builtin_amdgcn_mfma_f32_16x16x32_bf16(af[i], bfr[j], acc[i][j], 0, 0, 0);
    __syncthreads();
  }
  #pragma unroll
  for (int i = 0; i < 4; ++i)
    #pragma unroll
    for (int j = 0; j < 4; ++j)
      #pragma unroll
      for (int r = 0; r < 4; ++r) {
        int m = row0 + mb + i*16 + quad*4 + r;
        int n = col0 + nb + j*16 + lane16;
        C[(size_t)m*N + n] = acc[i][j][r];
      }
}

// ---------------- fused: gk = log_sigmoid(pre + b)/16, then in-chunk cumsum ----
// in-place on qkg cols 1024..1535. grid: 256 = b*128 + nc*4 + cs
__global__ __launch_bounds__(256) void gkcumsum_kernel(float* __restrict__ qkg,
                                                       const float* __restrict__ bias) {
  __shared__ float buf[CHUNKC][128];
  const int cs = blockIdx.x & 3;
  const int nc = (blockIdx.x >> 2) & 31;
  const int b  = blockIdx.x >> 7;
  const int t = threadIdx.x;
  const int bc = b*TDIM + nc*CHUNKC;
  const int col0 = cs*128;
  #pragma unroll
  for (int i = 0; i < 32; ++i) {
    int idx = t + 256*i;
    int c = idx >> 7, col = idx & 127;
    float s = qkg[(size_t)(bc + c)*QKG + 1024 + col0 + col] + bias[col0 + col];
    float ls = fminf(s, 0.f) - log1pf(expf(-fabsf(s)));
    buf[c][col] = ls * (1.0f/16.0f);
  }
  __syncthreads();
  if (t < 128) {
    float acc = 0.f;
    #pragma unroll
    for (int c = 0; c < CHUNKC; ++c) {
      acc += buf[c][t];
      buf[c][t] = acc;
    }
  }
  __syncthreads();
  #pragma unroll
  for (int i = 0; i < 32; ++i) {
    int idx = t + 256*i;
    int c = idx >> 7, col = idx & 127;
    qkg[(size_t)(bc + c)*QKG + 1024 + col0 + col] = buf[c][col];
  }
}

// ---------------- per-chunk state increment (MFMA): U[v][k] = sum_c v[c][v]*kbar[c][k] ----
// grid: 256 blocks = nc*8 + bh; 256 threads (4 waves).
__global__ __launch_bounds__(256) void state_chunk_kernel(const float* __restrict__ qkg,
                                                          const float* __restrict__ vgb,
                                                          float* __restrict__ U,
                                                          float* __restrict__ dec) {
  const int bh = blockIdx.x & 7;
  const int nc = blockIdx.x >> 3;
  const int b = bh >> 2, h = bh & 3;
  const int t = threadIdx.x;
  const int w = t >> 6, l = t & 63;
  const int lane16 = l & 15, quad = l >> 4;
  __shared__ hbf kbarT[DK][72];     // [k][c], 16B-aligned rows
  __shared__ hbf vT[DV][72];        // [v][c]
  __shared__ float glast[DK];
  const int bc = b*TDIM + nc*CHUNKC;
  if (t < DK) {
    float gl = qkg[(size_t)(bc + 63)*QKG + 1024 + h*DK + t];
    glast[t] = gl;
    dec[((size_t)nc*8 + bh)*DK + t] = expf(gl);
  }
  __syncthreads();
  #pragma unroll
  for (int i = 0; i < 32; ++i) {
    int idx = t + 256*i;
    int c = idx >> 7, kk = idx & 127;
    float g  = qkg[(size_t)(bc + c)*QKG + 1024 + h*DK + kk];
    float kv = qkg[(size_t)(bc + c)*QKG +  512 + h*DK + kk];
    kbarT[kk][c] = __float2bfloat16(kv * expf(glast[kk] - g));
  }
  #pragma unroll
  for (int i = 0; i < 64; ++i) {
    int idx = t + 256*i;
    int c = idx >> 8, col = idx & 255;
    vT[col][c] = __float2bfloat16(vgb[(size_t)(bc + c)*VGN + h*DV + col]);
  }
  __syncthreads();
  // wave w: v-strip w*64 (4 m-tiles) x full k (8 n-tiles), K=64 (2 steps)
  f32x4 acc[4][8] = {};
  #pragma unroll
  for (int kc = 0; kc < 2; ++kc) {
    bf16x8 av[4], bk[8];
    #pragma unroll
    for (int i = 0; i < 4; ++i)
      av[i] = *(const bf16x8*)&vT[w*64 + i*16 + lane16][kc*32 + quad*8];
    #pragma unroll
    for (int j = 0; j < 8; ++j)
      bk[j] = *(const bf16x8*)&kbarT[j*16 + lane16][kc*32 + quad*8];
    #pragma unroll
    for (int i = 0; i < 4; ++i)
      #pragma unroll
      for (int j = 0; j < 8; ++j)
        acc[i][j] = __builtin_amdgcn_mfma_f32_16x16x32_bf16(av[i], bk[j], acc[i][j], 0, 0, 0);
  }
  float* ub = U + ((size_t)nc*8 + bh)*((size_t)DK*DV);
  #pragma unroll
  for (int i = 0; i < 4; ++i)
    #pragma unroll
    for (int j = 0; j < 8; ++j)
      #pragma unroll
      for (int r = 0; r < 4; ++r) {
        int v = w*64 + i*16 + quad*4 + r;
        int k = j*16 + lane16;
        ub[(size_t)v*DK + k] = acc[i][j][r];
      }
}

// ---------------- elementwise scan over chunks: reads U fp32, writes S_prev bf16 ----
__global__ __launch_bounds__(256) void state_scan_kernel(const float* __restrict__ U,
                                                         const float* __restrict__ dec,
                                                         hbf* __restrict__ Spb) {
  const int e = blockIdx.x*256 + threadIdx.x;   // 0 .. 262143
  const int k = e & 127;
  const int bh = e >> 15;
  float S = 0.f;
  for (int nc = 0; nc < NC; ++nc) {
    float u = U[(size_t)nc*STRIDE_ST + e];
    Spb[(size_t)nc*STRIDE_ST + e] = __float2bfloat16(S);
    S = S * dec[((size_t)nc*8 + bh)*DK + k] + u;
  }
}

// ---------------- per-chunk output (MFMA): tril(qg kg^T), qg@S + A@v, RMSNorm, gate ----
// grid: 256 blocks = nc*8 + b*4 + h; 256 threads (4 waves).
__global__ __launch_bounds__(256) void out_kernel(const float* __restrict__ qkg,
                                                  const float* __restrict__ vgb,
                                                  const hbf* __restrict__ Spb,
                                                  const float* __restrict__ gnw,
                                                  hbf* __restrict__ obf) {
  const int blk = blockIdx.x;
  const int h = blk & 3, b = (blk >> 2) & 1, nc = blk >> 3;
  const int t = threadIdx.x;
  const int w = t >> 6, l = t & 63;
  const int lane16 = l & 15, quad = l >> 4;

  __shared__ __align__(16) unsigned char smem[64768];
  hbf (*qgs)[136] = (hbf(*)[136])(smem);                 // 17408 B
  hbf (*Ald)[72]  = (hbf(*)[72]) (smem + 17408);         //  9216 B
  hbf (*kgs)[136] = (hbf(*)[136])(smem + 26624);         // 17408 B (phase 1)
  hbf (*vT)[72]   = (hbf(*)[72]) (smem + 26624);         // 36864 B (phase 2, aliases kgs)
  float* ssum     = (float*)     (smem + 63488);         // 64*4
  float* invb     = (float*)     (smem + 64512);         // 64

  const float scale = 0.088388347648318447f;  // 128^-0.5
  const int bc = b*TDIM + nc*CHUNKC;

  // ---- stage qg, kg (bf16) ----
  #pragma unroll
  for (int i = 0; i < 32; ++i) {
    int idx = t + 256*i;
    int c = idx >> 7, kk = idx & 127;
    size_t rb = (size_t)(bc + c)*QKG + h*DK;
    float g = qkg[rb + 1024 + (0)] ; // placeholder avoided below
    g = qkg[rb + 1024 + kk - h*DK + h*DK]; // (kept simple)
    g = qkg[(size_t)(bc + c)*QKG + 1024 + h*DK + kk];
    qgs[c][kk] = __float2bfloat16(qkg[(size_t)(bc + c)*QKG + h*DK + kk] * expf(g) * scale);
    kgs[c][kk] = __float2bfloat16(qkg[(size_t)(bc + c)*QKG + 512 + h*DK + kk] * expf(-g));
  }
  __syncthreads();

  // ---- phase 1: A = tril(qg @ kg^T), wave w does rows w*16..w*16+15 ----
  f32x4 acc1[4] = {};
  #pragma unroll
  for (int kc = 0; kc < 4; ++kc) {
    bf16x8 af = *(const bf16x8*)&qgs[w*16 + lane16][kc*32 + quad*8];
    #pragma unroll
    for (int j = 0; j < 4; ++j) {
      bf16x8 bf = *(const bf16x8*)&kgs[j*16 + lane16][kc*32 + quad*8];
      acc1[j] = __builtin_amdgcn_mfma_f32_16x16x32_bf16(af, bf, acc1[j], 0, 0, 0);
    }
  }
  __syncthreads();   // all kgs reads done before vT overwrites

  // ---- store masked A (bf16) + stage vT (bf16, [v][c]) ----
  #pragma unroll
  for (int j = 0; j < 4; ++j)
    #pragma unroll
    for (int r = 0; r < 4; ++r) {
      int cr = w*16 + quad*4 + r;
      int cc = j*16 + lane16;
      Ald[cr][cc] = __float2bfloat16(cc <= cr ? acc1[j][r] : 0.f);
    }
  #pragma unroll
  for (int i = 0; i < 64; ++i) {
    int e = t + 256*i;
    int c = e >> 8, col = e & 255;
    vT[col][c] = __float2bfloat16(vgb[(size_t)(bc + c)*VGN + h*DV + col]);
  }
  __syncthreads();

  // ---- phase 2: o = qg @ S_prev + A @ v ; wave w owns v-col strip w*64 ----
  const hbf* SpB = Spb + ((size_t)nc*8 + (b*HH + h))*((size_t)DK*DV);
  f32x4 acc[4][4] = {};
  #pragma unroll
  for (int kc = 0; kc < 4; ++kc) {
    bf16x8 af[4], bs[4];
    #pragma unroll
    for (int i = 0; i < 4; ++i)
      af[i] = *(const bf16x8*)&qgs[i*16 + lane16][kc*32 + quad*8];
    #pragma unroll
    for (int j = 0; j < 4; ++j) {
      int n = w*64 + j*16 + lane16;
      bs[j] = *(const bf16x8*)(SpB + (size_t)n*DK + kc*32 + quad*8);
    }
    #pragma unroll
    for (int i = 0; i < 4; ++i)
      #pragma unroll
      for (int j = 0; j < 4; ++j)
        acc[i][j] = __builtin_amdgcn_mfma_f32_16x16x32_bf16(af[i], bs[j], acc[i][j], 0, 0, 0);
  }
  #pragma unroll
  for (int kc = 0; kc < 2; ++kc) {
    bf16x8 aa[4], bv[4];
    #pragma unroll
    for (int i = 0; i < 4; ++i)
      aa[i] = *(const bf16x8*)&Ald[i*16 + lane16][kc*32 + quad*8];
    #pragma unroll
    for (int j = 0; j < 4; ++j)
      bv[j] = *(const bf16x8*)&vT[w*64 + j*16 + lane16][kc*32 + quad*8];
    #pragma unroll
    for (int i = 0; i < 4; ++i)
      #pragma unroll
      for (int j = 0; j < 4; ++j)
        acc[i][j] = __builtin_amdgcn_mfma_f32_16x16x32_bf16(aa[i], bv[j], acc[i][j], 0, 0, 0);
  }

  // ---- epilogue: RMSNorm over DV=256 + silu gate, write bf16 ----
  #pragma unroll
  for (int i = 0; i < 4; ++i)
    #pragma unroll
    for (int r = 0; r < 4; ++r) {
      float s = 0.f;
      #pragma unroll
      for (int j = 0; j < 4; ++j) s += acc[i][j][r]*acc[i][j][r];
      s += __shfl_xor(s, 1); s += __shfl_xor(s, 2);
      s += __shfl_xor(s, 4); s += __shfl_xor(s, 8);
      if (lane16 == 0) ssum[(i*16 + quad*4 + r)*4 + w] = s;
    }
  __syncthreads();
  if (t < 64) {
    float tot = ssum[t*4] + ssum[t*4+1] + ssum[t*4+2] + ssum[t*4+3];
    invb[t] = rsqrtf(tot * (1.0f/DV) + 1e-6f);
  }
  __syncthreads();
  float gnwv[4];
  #pragma unroll
  for (int j = 0; j < 4; ++j) gnwv[j] = gnw[w*64 + j*16 + lane16];
  #pragma unroll
  for (int i = 0; i < 4; ++i)
    #pragma unroll
    for (int r = 0; r < 4; ++r) {
      int m = i*16 + quad*4 + r;
      float inv = invb[m];
      size_t grow_ = (size_t)(bc + m)*VGN + 1024 + h*DV + w*64;
      size_t orow_ = (size_t)(bc + m)*VD + h*DV + w*64;
      #pragma unroll
      for (int j = 0; j < 4; ++j) {
        float gv = vgb[grow_ + j*16 + lane16];
        float sig = 1.f / (1.f + expf(-gv));
        float val = acc[i][j][r] * inv * gnwv[j];
        obf[orow_ + j*16 + lane16] = __float2bfloat16(val * (gv * sig));
      }
    }
}

extern "C" void kernel_launch(void* const* d_in, const int* in_sizes, int n_in,
                              void* d_out, int out_size, void* d_ws, size_t ws_size,
                              hipStream_t stream) {
  const float* x    = (const float*)d_in[0];
  const float* Wq   = (const float*)d_in[1];
  const float* Wk   = (const float*)d_in[2];
  const float* Wv   = (const float*)d_in[3];
  const float* Wg   = (const float*)d_in[4];
  const float* Wgk1 = (const float*)d_in[5];
  const float* Wgk2 = (const float*)d_in[6];
  const float* bgk2 = (const float*)d_in[7];
  const float* gnw  = (const float*)d_in[8];
  const float* Wo   = (const float*)d_in[9];
  float* out = (float*)d_out;

  float* ws  = (float*)d_ws;
  float* qkg = ws;                                   // 4096*1536 fp32 (q|k|gk->G)
  float* vgb = qkg + (size_t)MTOT*QKG;               // 4096*2048 fp32 (v|g)
  float* U   = vgb + (size_t)MTOT*VGN;               // 32*262144 fp32 ([v][k])
  float* dec = U   + (size_t)NC*STRIDE_ST;           // 32*8*128
  float* bfr = dec + (size_t)NC*BDIM*HH*DK;          // bf16 region start
  hbf* xbf   = (hbf*)bfr;                            // 4096*1024
  hbf* wtqkg = xbf   + (size_t)MTOT*DDIM;            // 1536*1024 (Wq^T|Wk^T|Wc^T)
  hbf* wtvg  = wtqkg + (size_t)QKG*DDIM;             // 2048*1024
  hbf* wto   = wtvg  + (size_t)VGN*DDIM;             // 1024*1024
  hbf* Spb   = wto   + (size_t)DDIM*DDIM;            // 32*262144 bf16 S_prev [v][k]
  hbf* obf   = (hbf*)U;                              // alias: U dead before out_kernel

  cast_bf16_kernel<<<MTOT*DDIM/4/256, 256, 0, stream>>>(x, xbf);
  transpose_cast_kernel<<<dim3(512/32, DDIM/32), 256, 0, stream>>>(Wq, wtqkg, DDIM, 512);
  transpose_cast_kernel<<<dim3(512/32, DDIM/32), 256, 0, stream>>>(Wk, wtqkg + (size_t)512*DDIM, DDIM, 512);
  wcomp_kernel<<<512*1024/256, 256, 0, stream>>>(Wgk1, Wgk2, wtqkg + (size_t)1024*DDIM);
  transpose_cast_kernel<<<dim3(1024/32, DDIM/32), 256, 0, stream>>>(Wv, wtvg, DDIM, 1024);
  transpose_cast_kernel<<<dim3(1024/32, DDIM/32), 256, 0, stream>>>(Wg, wtvg + (size_t)1024*DDIM, DDIM, 1024);
  transpose_cast_kernel<<<dim3(1024/32, DDIM/32), 256, 0, stream>>>(Wo, wto, DDIM, 1024);

  gemm_bt<<<dim3(QKG/128, MTOT/128), 256, 0, stream>>>(xbf, wtqkg, qkg, MTOT, QKG, DDIM);
  gemm_bt<<<dim3(VGN/128, MTOT/128), 256, 0, stream>>>(xbf, wtvg, vgb, MTOT, VGN, DDIM);

  gkcumsum_kernel<<<256, 256, 0, stream>>>(qkg, bgk2);
  state_chunk_kernel<<<NC*BDIM*HH, 256, 0, stream>>>(qkg, vgb, U, dec);
  state_scan_kernel<<<(int)(STRIDE_ST/256), 256, 0, stream>>>(U, dec, Spb);
  out_kernel<<<NC*BDIM*HH, 256, 0, stream>>>(qkg, vgb, Spb, gnw, obf);
  gemm_bt<<<dim3(DDIM/128, MTOT/128), 256, 0, stream>>>(obf, wto, out, MTOT, DDIM, DDIM);
}

// Round 7
// 254.600 us; speedup vs baseline: 7.5546x; 1.0321x over previous
//
#include <hip/hip_runtime.h>
#include <hip/hip_bf16.h>

#define BDIM 2
#define TDIM 2048
#define DDIM 1024
#define HH 4
#define KD 512
#define VD 1024
#define DK 128
#define DV 256
#define NC 32
#define CHUNKC 64
#define MTOT (BDIM*TDIM)   // 4096
#define NALL 3584          // q|k (1024) | gk (512) | v|g (2048)
#define STRIDE_ST ((size_t)BDIM*HH*DK*DV)   // 262144 elems per chunk of states

typedef __bf16 bf16x8 __attribute__((ext_vector_type(8)));
typedef float  f32x4  __attribute__((ext_vector_type(4)));
typedef __hip_bfloat16 hbf;

__device__ __forceinline__ void async_copy16(const void* g, void* l) {
  __builtin_amdgcn_global_load_lds(
      (const __attribute__((address_space(1))) void*)g,
      (__attribute__((address_space(3))) void*)l, 16, 0, 0);
}

// ---------------- cast x (fp32 -> bf16), 4 elems/thread ----------------
__global__ void cast_bf16_kernel(const float* __restrict__ src, hbf* __restrict__ dst) {
  int t = blockIdx.x*256 + threadIdx.x;
  float4 v = ((const float4*)src)[t];
  union { hbf h[4]; uint2 u; } o;
  o.h[0] = __float2bfloat16(v.x); o.h[1] = __float2bfloat16(v.y);
  o.h[2] = __float2bfloat16(v.z); o.h[3] = __float2bfloat16(v.w);
  ((uint2*)dst)[t] = o.u;
}

// ---------------- transpose + cast: Wt[n][k] = W[k][n] ----------------
__global__ void transpose_cast_kernel(const float* __restrict__ W, hbf* __restrict__ Wt,
                                      int K, int N) {
  __shared__ float tile[32][33];
  const int bx = blockIdx.x, by = blockIdx.y;
  const int tx = threadIdx.x & 31, ty = threadIdx.x >> 5;
  #pragma unroll
  for (int r = ty; r < 32; r += 8)
    tile[r][tx] = W[(size_t)(by*32 + r)*N + bx*32 + tx];
  __syncthreads();
  #pragma unroll
  for (int r = ty; r < 32; r += 8)
    Wt[(size_t)(bx*32 + r)*K + by*32 + tx] = __float2bfloat16(tile[tx][r]);
}

// ---------------- Wc^T[n][k] = (Wgk1 @ Wgk2)^T, bf16 ----------------
__global__ void wcomp_kernel(const float* __restrict__ W1, const float* __restrict__ W2,
                             hbf* __restrict__ Wct) {
  int idx = blockIdx.x*256 + threadIdx.x;   // 512*1024 threads
  int k = idx & 1023, n = idx >> 10;
  float s = 0.f;
  #pragma unroll
  for (int r = 0; r < 16; ++r) s += W1[k*16 + r] * W2[r*KD + n];
  Wct[(size_t)n*DDIM + k] = __float2bfloat16(s);
}

// ---------------- MFMA GEMM: A[M,K] bf16 @ Bt[N,K]^T bf16 ----------------
// MODE 0: fp32 C[M,N].   MODE 1: mixed epilogue (qk bf16 | G fp32 | vg bf16).
template <int MODE>
__global__ __launch_bounds__(256) void gemm_bt(const hbf* __restrict__ A,
                                               const hbf* __restrict__ Bt,
                                               float* __restrict__ Cf,
                                               hbf* __restrict__ Cq,
                                               hbf* __restrict__ Cv,
                                               int M, int N, int K) {
  __shared__ hbf As[128][32];
  __shared__ hbf Bs[128][32];
  const int t = threadIdx.x;
  const int w = t >> 6, l = t & 63;
  const int lr = l >> 2, lc = (l & 3)*8;
  const int lane16 = l & 15, quad = l >> 4;
  const int row0 = blockIdx.y*128, col0 = blockIdx.x*128;
  const int mb = (w >> 1)*64, nb = (w & 1)*64;

  const hbf* ga = A  + (size_t)(row0 + w*32 + lr)*K + lc;
  const hbf* gb = Bt + (size_t)(col0 + w*32 + lr)*K + lc;
  hbf* la0 = &As[w*32][0];      hbf* la1 = &As[w*32 + 16][0];
  hbf* lb0 = &Bs[w*32][0];      hbf* lb1 = &Bs[w*32 + 16][0];
  const size_t rstep = (size_t)16*K;

  f32x4 acc[4][4] = {};
  for (int k0 = 0; k0 < K; k0 += 32) {
    async_copy16(ga,         la0);
    async_copy16(ga + rstep, la1);
    async_copy16(gb,         lb0);
    async_copy16(gb + rstep, lb1);
    ga += 32; gb += 32;
    __syncthreads();
    bf16x8 af[4], bfr[4];
    #pragma unroll
    for (int i = 0; i < 4; ++i)
      af[i] = *(const bf16x8*)&As[mb + i*16 + lane16][quad*8];
    #pragma unroll
    for (int j = 0; j < 4; ++j)
      bfr[j] = *(const bf16x8*)&Bs[nb + j*16 + lane16][quad*8];
    #pragma unroll
    for (int i = 0; i < 4; ++i)
      #pragma unroll
      for (int j = 0; j < 4; ++j)
        acc[i][j] = __builtin_amdgcn_mfma_f32_16x16x32_bf16(af[i], bfr[j], acc[i][j], 0, 0, 0);
    __syncthreads();
  }
  #pragma unroll
  for (int i = 0; i < 4; ++i)
    #pragma unroll
    for (int j = 0; j < 4; ++j)
      #pragma unroll
      for (int r = 0; r < 4; ++r) {
        int m = row0 + mb + i*16 + quad*4 + r;
        int n = col0 + nb + j*16 + lane16;
        float v = acc[i][j][r];
        if (MODE == 0) {
          Cf[(size_t)m*N + n] = v;
        } else {
          if (col0 < 1024)       Cq[(size_t)m*1024 + n] = __float2bfloat16(v);
          else if (col0 < 1536)  Cf[(size_t)m*512  + n - 1024] = v;
          else                   Cv[(size_t)m*2048 + n - 1536] = __float2bfloat16(v);
        }
      }
}

// ---------------- fused: G = cumsum(log_sigmoid(pre + b)/16) in place on Gb ----
// grid: 256 = b*128 + nc*4 + cs
__global__ __launch_bounds__(256) void gkcumsum_kernel(float* __restrict__ Gb,
                                                       const float* __restrict__ bias) {
  __shared__ float buf[CHUNKC][128];
  const int cs = blockIdx.x & 3;
  const int nc = (blockIdx.x >> 2) & 31;
  const int b  = blockIdx.x >> 7;
  const int t = threadIdx.x;
  const int bc = b*TDIM + nc*CHUNKC;
  const int col0 = cs*128;
  #pragma unroll
  for (int i = 0; i < 32; ++i) {
    int idx = t + 256*i;
    int c = idx >> 7, col = idx & 127;
    float s = Gb[(size_t)(bc + c)*KD + col0 + col] + bias[col0 + col];
    float ls = fminf(s, 0.f) - log1pf(expf(-fabsf(s)));
    buf[c][col] = ls * (1.0f/16.0f);
  }
  __syncthreads();
  if (t < 128) {
    float acc = 0.f;
    #pragma unroll
    for (int c = 0; c < CHUNKC; ++c) {
      acc += buf[c][t];
      buf[c][t] = acc;
    }
  }
  __syncthreads();
  #pragma unroll
  for (int i = 0; i < 32; ++i) {
    int idx = t + 256*i;
    int c = idx >> 7, col = idx & 127;
    Gb[(size_t)(bc + c)*KD + col0 + col] = buf[c][col];
  }
}

// ---------------- per-chunk state increment (MFMA): U[v][k] bf16 ----------------
// grid: 256 blocks = nc*8 + bh; 256 threads (4 waves).
__global__ __launch_bounds__(256) void state_chunk_kernel(const hbf* __restrict__ qkbf,
                                                          const hbf* __restrict__ vgbf,
                                                          const float* __restrict__ Gb,
                                                          hbf* __restrict__ Ub,
                                                          float* __restrict__ dec) {
  const int bh = blockIdx.x & 7;
  const int nc = blockIdx.x >> 3;
  const int b = bh >> 2, h = bh & 3;
  const int t = threadIdx.x;
  const int w = t >> 6, l = t & 63;
  const int lane16 = l & 15, quad = l >> 4;
  __shared__ hbf kbarT[DK][72];     // [k][c]
  __shared__ hbf vT[DV][72];        // [v][c]
  __shared__ float glast[DK];
  const int bc = b*TDIM + nc*CHUNKC;
  if (t < DK) {
    float gl = Gb[(size_t)(bc + 63)*KD + h*DK + t];
    glast[t] = gl;
    dec[((size_t)nc*8 + bh)*DK + t] = expf(gl);
  }
  __syncthreads();
  #pragma unroll
  for (int i = 0; i < 32; ++i) {
    int idx = t + 256*i;
    int c = idx >> 7, kk = idx & 127;
    float g  = Gb[(size_t)(bc + c)*KD + h*DK + kk];
    float kv = __bfloat162float(qkbf[(size_t)(bc + c)*1024 + 512 + h*DK + kk]);
    kbarT[kk][c] = __float2bfloat16(kv * expf(glast[kk] - g));
  }
  #pragma unroll
  for (int i = 0; i < 64; ++i) {
    int idx = t + 256*i;
    int c = idx >> 8, col = idx & 255;
    vT[col][c] = vgbf[(size_t)(bc + c)*2048 + h*DV + col];
  }
  __syncthreads();
  f32x4 acc[4][8] = {};
  #pragma unroll
  for (int kc = 0; kc < 2; ++kc) {
    bf16x8 av[4], bk[8];
    #pragma unroll
    for (int i = 0; i < 4; ++i)
      av[i] = *(const bf16x8*)&vT[w*64 + i*16 + lane16][kc*32 + quad*8];
    #pragma unroll
    for (int j = 0; j < 8; ++j)
      bk[j] = *(const bf16x8*)&kbarT[j*16 + lane16][kc*32 + quad*8];
    #pragma unroll
    for (int i = 0; i < 4; ++i)
      #pragma unroll
      for (int j = 0; j < 8; ++j)
        acc[i][j] = __builtin_amdgcn_mfma_f32_16x16x32_bf16(av[i], bk[j], acc[i][j], 0, 0, 0);
  }
  hbf* ub = Ub + ((size_t)nc*8 + bh)*((size_t)DK*DV);
  #pragma unroll
  for (int i = 0; i < 4; ++i)
    #pragma unroll
    for (int j = 0; j < 8; ++j)
      #pragma unroll
      for (int r = 0; r < 4; ++r) {
        int v = w*64 + i*16 + quad*4 + r;
        int k = j*16 + lane16;
        ub[(size_t)v*DK + k] = __float2bfloat16(acc[i][j][r]);
      }
}

// ---------------- scan over chunks: reads U bf16, fp32 accum, writes S_prev bf16 ----
// 2 elems/thread (bf16x2), 131072 threads.
__global__ __launch_bounds__(256) void state_scan_kernel(const hbf* __restrict__ Ub,
                                                         const float* __restrict__ dec,
                                                         hbf* __restrict__ Spb) {
  const int p = blockIdx.x*256 + threadIdx.x;   // pair index 0..131071
  const size_t e = (size_t)p*2;
  const int k = (int)(e & 127);
  const int bh = (int)(e >> 15);
  float S0 = 0.f, S1 = 0.f;
  for (int nc = 0; nc < NC; ++nc) {
    const size_t off = (size_t)nc*STRIDE_ST + e;
    uint uu = *(const uint*)(Ub + off);
    hbf u0 = *(const hbf*)&uu;
    hbf u1 = *((const hbf*)&uu + 1);
    union { hbf h[2]; uint u; } ov;
    ov.h[0] = __float2bfloat16(S0); ov.h[1] = __float2bfloat16(S1);
    *(uint*)(Spb + off) = ov.u;
    float2 d = *(const float2*)(dec + ((size_t)nc*8 + bh)*DK + k);
    S0 = S0 * d.x + __bfloat162float(u0);
    S1 = S1 * d.y + __bfloat162float(u1);
  }
}

// ---------------- per-chunk output (MFMA): tril(qg kg^T), qg@S + A@v, RMSNorm, gate ----
// grid: 256 blocks = nc*8 + b*4 + h; 256 threads (4 waves).
__global__ __launch_bounds__(256) void out_kernel(const hbf* __restrict__ qkbf,
                                                  const hbf* __restrict__ vgbf,
                                                  const float* __restrict__ Gb,
                                                  const hbf* __restrict__ Spb,
                                                  const float* __restrict__ gnw,
                                                  hbf* __restrict__ obf) {
  const int blk = blockIdx.x;
  const int h = blk & 3, b = (blk >> 2) & 1, nc = blk >> 3;
  const int t = threadIdx.x;
  const int w = t >> 6, l = t & 63;
  const int lane16 = l & 15, quad = l >> 4;

  __shared__ __align__(16) unsigned char smem[64768];
  hbf (*qgs)[136] = (hbf(*)[136])(smem);                 // 17408 B
  hbf (*Ald)[72]  = (hbf(*)[72]) (smem + 17408);         //  9216 B
  hbf (*kgs)[136] = (hbf(*)[136])(smem + 26624);         // 17408 B (phase 1)
  hbf (*vT)[72]   = (hbf(*)[72]) (smem + 26624);         // 36864 B (phase 2, aliases kgs)
  float* ssum     = (float*)     (smem + 63488);         // 64*4
  float* invb     = (float*)     (smem + 64512);         // 64

  const float scale = 0.088388347648318447f;  // 128^-0.5
  const int bc = b*TDIM + nc*CHUNKC;

  // ---- stage qg, kg (bf16) ----
  #pragma unroll
  for (int i = 0; i < 32; ++i) {
    int idx = t + 256*i;
    int c = idx >> 7, kk = idx & 127;
    float g = Gb[(size_t)(bc + c)*KD + h*DK + kk];
    float qv = __bfloat162float(qkbf[(size_t)(bc + c)*1024 + h*DK + kk]);
    float kv = __bfloat162float(qkbf[(size_t)(bc + c)*1024 + 512 + h*DK + kk]);
    qgs[c][kk] = __float2bfloat16(qv * expf(g) * scale);
    kgs[c][kk] = __float2bfloat16(kv * expf(-g));
  }
  __syncthreads();

  // ---- phase 1: A = tril(qg @ kg^T) ----
  f32x4 acc1[4] = {};
  #pragma unroll
  for (int kc = 0; kc < 4; ++kc) {
    bf16x8 af = *(const bf16x8*)&qgs[w*16 + lane16][kc*32 + quad*8];
    #pragma unroll
    for (int j = 0; j < 4; ++j) {
      bf16x8 bf = *(const bf16x8*)&kgs[j*16 + lane16][kc*32 + quad*8];
      acc1[j] = __builtin_amdgcn_mfma_f32_16x16x32_bf16(af, bf, acc1[j], 0, 0, 0);
    }
  }
  __syncthreads();

  // ---- store masked A (bf16) + stage vT (bf16, [v][c]) ----
  #pragma unroll
  for (int j = 0; j < 4; ++j)
    #pragma unroll
    for (int r = 0; r < 4; ++r) {
      int cr = w*16 + quad*4 + r;
      int cc = j*16 + lane16;
      Ald[cr][cc] = __float2bfloat16(cc <= cr ? acc1[j][r] : 0.f);
    }
  #pragma unroll
  for (int i = 0; i < 64; ++i) {
    int e = t + 256*i;
    int c = e >> 8, col = e & 255;
    vT[col][c] = vgbf[(size_t)(bc + c)*2048 + h*DV + col];
  }
  __syncthreads();

  // ---- phase 2: o = qg @ S_prev + A @ v ----
  const hbf* SpB = Spb + ((size_t)nc*8 + (b*HH + h))*((size_t)DK*DV);
  f32x4 acc[4][4] = {};
  #pragma unroll
  for (int kc = 0; kc < 4; ++kc) {
    bf16x8 af[4], bs[4];
    #pragma unroll
    for (int i = 0; i < 4; ++i)
      af[i] = *(const bf16x8*)&qgs[i*16 + lane16][kc*32 + quad*8];
    #pragma unroll
    for (int j = 0; j < 4; ++j) {
      int n = w*64 + j*16 + lane16;
      bs[j] = *(const bf16x8*)(SpB + (size_t)n*DK + kc*32 + quad*8);
    }
    #pragma unroll
    for (int i = 0; i < 4; ++i)
      #pragma unroll
      for (int j = 0; j < 4; ++j)
        acc[i][j] = __builtin_amdgcn_mfma_f32_16x16x32_bf16(af[i], bs[j], acc[i][j], 0, 0, 0);
  }
  #pragma unroll
  for (int kc = 0; kc < 2; ++kc) {
    bf16x8 aa[4], bv[4];
    #pragma unroll
    for (int i = 0; i < 4; ++i)
      aa[i] = *(const bf16x8*)&Ald[i*16 + lane16][kc*32 + quad*8];
    #pragma unroll
    for (int j = 0; j < 4; ++j)
      bv[j] = *(const bf16x8*)&vT[w*64 + j*16 + lane16][kc*32 + quad*8];
    #pragma unroll
    for (int i = 0; i < 4; ++i)
      #pragma unroll
      for (int j = 0; j < 4; ++j)
        acc[i][j] = __builtin_amdgcn_mfma_f32_16x16x32_bf16(aa[i], bv[j], acc[i][j], 0, 0, 0);
  }

  // ---- epilogue: RMSNorm over DV=256 + silu gate, write bf16 ----
  #pragma unroll
  for (int i = 0; i < 4; ++i)
    #pragma unroll
    for (int r = 0; r < 4; ++r) {
      float s = 0.f;
      #pragma unroll
      for (int j = 0; j < 4; ++j) s += acc[i][j][r]*acc[i][j][r];
      s += __shfl_xor(s, 1); s += __shfl_xor(s, 2);
      s += __shfl_xor(s, 4); s += __shfl_xor(s, 8);
      if (lane16 == 0) ssum[(i*16 + quad*4 + r)*4 + w] = s;
    }
  __syncthreads();
  if (t < 64) {
    float tot = ssum[t*4] + ssum[t*4+1] + ssum[t*4+2] + ssum[t*4+3];
    invb[t] = rsqrtf(tot * (1.0f/DV) + 1e-6f);
  }
  __syncthreads();
  float gnwv[4];
  #pragma unroll
  for (int j = 0; j < 4; ++j) gnwv[j] = gnw[w*64 + j*16 + lane16];
  #pragma unroll
  for (int i = 0; i < 4; ++i)
    #pragma unroll
    for (int r = 0; r < 4; ++r) {
      int m = i*16 + quad*4 + r;
      float inv = invb[m];
      size_t grow_ = (size_t)(bc + m)*2048 + 1024 + h*DV + w*64;
      size_t orow_ = (size_t)(bc + m)*VD + h*DV + w*64;
      #pragma unroll
      for (int j = 0; j < 4; ++j) {
        float gv = __bfloat162float(vgbf[grow_ + j*16 + lane16]);
        float sig = 1.f / (1.f + expf(-gv));
        float val = acc[i][j][r] * inv * gnwv[j];
        obf[orow_ + j*16 + lane16] = __float2bfloat16(val * (gv * sig));
      }
    }
}

extern "C" void kernel_launch(void* const* d_in, const int* in_sizes, int n_in,
                              void* d_out, int out_size, void* d_ws, size_t ws_size,
                              hipStream_t stream) {
  const float* x    = (const float*)d_in[0];
  const float* Wq   = (const float*)d_in[1];
  const float* Wk   = (const float*)d_in[2];
  const float* Wv   = (const float*)d_in[3];
  const float* Wg   = (const float*)d_in[4];
  const float* Wgk1 = (const float*)d_in[5];
  const float* Wgk2 = (const float*)d_in[6];
  const float* bgk2 = (const float*)d_in[7];
  const float* gnw  = (const float*)d_in[8];
  const float* Wo   = (const float*)d_in[9];
  float* out = (float*)d_out;

  float* ws  = (float*)d_ws;
  float* Gb  = ws;                                   // 4096*512 fp32 (gk pre -> G)
  float* dec = Gb  + (size_t)MTOT*KD;                // 32*8*128 fp32
  hbf* xbf   = (hbf*)(dec + (size_t)NC*BDIM*HH*DK);  // 4096*1024 bf16
  hbf* wtall = xbf   + (size_t)MTOT*DDIM;            // 3584*1024 bf16 (Wq|Wk|Wc|Wv|Wg)^T
  hbf* wto   = wtall + (size_t)NALL*DDIM;            // 1024*1024 bf16
  hbf* qkbf  = wto   + (size_t)DDIM*DDIM;            // 4096*1024 bf16 (q|k)
  hbf* vgbf  = qkbf  + (size_t)MTOT*1024;            // 4096*2048 bf16 (v|g)
  hbf* Ub    = vgbf  + (size_t)MTOT*2048;            // 32*262144 bf16 (U, [v][k])
  hbf* Spb   = Ub    + (size_t)NC*STRIDE_ST;         // 32*262144 bf16 (S_prev, [v][k])
  hbf* obf   = Ub;                                   // alias: U dead before out_kernel

  cast_bf16_kernel<<<MTOT*DDIM/4/256, 256, 0, stream>>>(x, xbf);
  transpose_cast_kernel<<<dim3(512/32, DDIM/32), 256, 0, stream>>>(Wq, wtall, DDIM, 512);
  transpose_cast_kernel<<<dim3(512/32, DDIM/32), 256, 0, stream>>>(Wk, wtall + (size_t)512*DDIM, DDIM, 512);
  wcomp_kernel<<<512*1024/256, 256, 0, stream>>>(Wgk1, Wgk2, wtall + (size_t)1024*DDIM);
  transpose_cast_kernel<<<dim3(1024/32, DDIM/32), 256, 0, stream>>>(Wv, wtall + (size_t)1536*DDIM, DDIM, 1024);
  transpose_cast_kernel<<<dim3(1024/32, DDIM/32), 256, 0, stream>>>(Wg, wtall + (size_t)2560*DDIM, DDIM, 1024);
  transpose_cast_kernel<<<dim3(1024/32, DDIM/32), 256, 0, stream>>>(Wo, wto, DDIM, 1024);

  gemm_bt<1><<<dim3(NALL/128, MTOT/128), 256, 0, stream>>>(xbf, wtall, Gb, qkbf, vgbf, MTOT, NALL, DDIM);

  gkcumsum_kernel<<<256, 256, 0, stream>>>(Gb, bgk2);
  state_chunk_kernel<<<NC*BDIM*HH, 256, 0, stream>>>(qkbf, vgbf, Gb, Ub, dec);
  state_scan_kernel<<<(int)(STRIDE_ST/2/256), 256, 0, stream>>>(Ub, dec, Spb);
  out_kernel<<<NC*BDIM*HH, 256, 0, stream>>>(qkbf, vgbf, Gb, Spb, gnw, obf);
  gemm_bt<0><<<dim3(DDIM/128, MTOT/128), 256, 0, stream>>>(obf, wto, out, (hbf*)nullptr, (hbf*)nullptr, MTOT, DDIM, DDIM);
}

// Round 8
// 230.262 us; speedup vs baseline: 8.3531x; 1.1057x over previous
//
#include <hip/hip_runtime.h>
#include <hip/hip_bf16.h>

#define BDIM 2
#define TDIM 2048
#define DDIM 1024
#define HH 4
#define KD 512
#define VD 1024
#define DK 128
#define DV 256
#define NC 32
#define CHUNKC 64
#define MTOT (BDIM*TDIM)   // 4096
#define NALL 3584          // q|k (1024) | gk (512) | v|g (2048)
#define STRIDE_ST ((size_t)BDIM*HH*DK*DV)   // 262144 elems per chunk of states

typedef __bf16 bf16x8 __attribute__((ext_vector_type(8)));
typedef float  f32x4  __attribute__((ext_vector_type(4)));
typedef __hip_bfloat16 hbf;

__device__ __forceinline__ void async_copy16(const void* g, void* l) {
  __builtin_amdgcn_global_load_lds(
      (const __attribute__((address_space(1))) void*)g,
      (__attribute__((address_space(3))) void*)l, 16, 0, 0);
}

// ---------------- cast x (fp32 -> bf16), 4 elems/thread ----------------
__global__ void cast_bf16_kernel(const float* __restrict__ src, hbf* __restrict__ dst) {
  int t = blockIdx.x*256 + threadIdx.x;
  float4 v = ((const float4*)src)[t];
  union { hbf h[4]; uint2 u; } o;
  o.h[0] = __float2bfloat16(v.x); o.h[1] = __float2bfloat16(v.y);
  o.h[2] = __float2bfloat16(v.z); o.h[3] = __float2bfloat16(v.w);
  ((uint2*)dst)[t] = o.u;
}

// ---------------- one-shot weight prep: transpose+cast all W, compute Wc^T ----
// virtual rows 0..4607: [0,512)Wq [512,1024)Wk [1024,1536)Wc [1536,2560)Wv
// [2560,3584)Wg [3584,4608)Wo.  grid (144, 32), 256 thr.
__global__ void prep_weights(const float* __restrict__ Wq, const float* __restrict__ Wk,
                             const float* __restrict__ Wv, const float* __restrict__ Wg,
                             const float* __restrict__ Wo, const float* __restrict__ W1,
                             const float* __restrict__ W2,
                             hbf* __restrict__ wtall, hbf* __restrict__ wto) {
  __shared__ float tile[32][33];
  const int n0 = blockIdx.x*32, k0 = blockIdx.y*32;
  const int tx = threadIdx.x & 31, ty = threadIdx.x >> 5;
  if (n0 >= 1024 && n0 < 1536) {          // Wc = (Wgk1 @ Wgk2)^T, computed directly
    #pragma unroll
    for (int r = ty; r < 32; r += 8) {
      int n = n0 - 1024 + r, k = k0 + tx;
      float s = 0.f;
      #pragma unroll
      for (int j = 0; j < 16; ++j) s += W1[(size_t)k*16 + j] * W2[(size_t)j*KD + n];
      wtall[(size_t)(n0 + r)*DDIM + k] = __float2bfloat16(s);
    }
    return;
  }
  const float* W; int Nsrc, nloc; hbf* outp; int orow;
  if      (n0 < 512)  { W = Wq; Nsrc = 512;  nloc = n0;        outp = wtall; orow = n0; }
  else if (n0 < 1024) { W = Wk; Nsrc = 512;  nloc = n0 - 512;  outp = wtall; orow = n0; }
  else if (n0 < 2560) { W = Wv; Nsrc = 1024; nloc = n0 - 1536; outp = wtall; orow = n0; }
  else if (n0 < 3584) { W = Wg; Nsrc = 1024; nloc = n0 - 2560; outp = wtall; orow = n0; }
  else                { W = Wo; Nsrc = 1024; nloc = n0 - 3584; outp = wto;   orow = n0 - 3584; }
  #pragma unroll
  for (int r = ty; r < 32; r += 8)
    tile[r][tx] = W[(size_t)(k0 + r)*Nsrc + nloc + tx];
  __syncthreads();
  #pragma unroll
  for (int r = ty; r < 32; r += 8)
    outp[(size_t)(orow + r)*DDIM + k0 + tx] = __float2bfloat16(tile[tx][r]);
}

// ---------------- MFMA GEMM, BK=64 (split half-buffers, half the barriers) ----
// MODE 0: fp32 C[M,N].   MODE 1: mixed epilogue (qk bf16 | G fp32 | vg bf16).
template <int MODE>
__global__ __launch_bounds__(256) void gemm_bt(const hbf* __restrict__ A,
                                               const hbf* __restrict__ Bt,
                                               float* __restrict__ Cf,
                                               hbf* __restrict__ Cq,
                                               hbf* __restrict__ Cv,
                                               int M, int N, int K) {
  __shared__ hbf As0[128][32], As1[128][32];
  __shared__ hbf Bs0[128][32], Bs1[128][32];
  const int t = threadIdx.x;
  const int w = t >> 6, l = t & 63;
  const int lr = l >> 2, lc = (l & 3)*8;
  const int lane16 = l & 15, quad = l >> 4;
  const int row0 = blockIdx.y*128, col0 = blockIdx.x*128;
  const int mb = (w >> 1)*64, nb = (w & 1)*64;

  const hbf* ga = A  + (size_t)(row0 + w*32 + lr)*K + lc;
  const hbf* gb = Bt + (size_t)(col0 + w*32 + lr)*K + lc;
  hbf* la0 = &As0[w*32][0];   hbf* la1 = &As0[w*32 + 16][0];
  hbf* la2 = &As1[w*32][0];   hbf* la3 = &As1[w*32 + 16][0];
  hbf* lb0 = &Bs0[w*32][0];   hbf* lb1 = &Bs0[w*32 + 16][0];
  hbf* lb2 = &Bs1[w*32][0];   hbf* lb3 = &Bs1[w*32 + 16][0];
  const size_t rstep = (size_t)16*K;

  f32x4 acc[4][4] = {};
  for (int k0 = 0; k0 < K; k0 += 64) {
    async_copy16(ga,              la0);
    async_copy16(ga + rstep,      la1);
    async_copy16(ga + 32,         la2);
    async_copy16(ga + rstep + 32, la3);
    async_copy16(gb,              lb0);
    async_copy16(gb + rstep,      lb1);
    async_copy16(gb + 32,         lb2);
    async_copy16(gb + rstep + 32, lb3);
    ga += 64; gb += 64;
    __syncthreads();
    {
      bf16x8 af[4], bfr[4];
      #pragma unroll
      for (int i = 0; i < 4; ++i)
        af[i] = *(const bf16x8*)&As0[mb + i*16 + lane16][quad*8];
      #pragma unroll
      for (int j = 0; j < 4; ++j)
        bfr[j] = *(const bf16x8*)&Bs0[nb + j*16 + lane16][quad*8];
      #pragma unroll
      for (int i = 0; i < 4; ++i)
        #pragma unroll
        for (int j = 0; j < 4; ++j)
          acc[i][j] = __builtin_amdgcn_mfma_f32_16x16x32_bf16(af[i], bfr[j], acc[i][j], 0, 0, 0);
    }
    {
      bf16x8 af[4], bfr[4];
      #pragma unroll
      for (int i = 0; i < 4; ++i)
        af[i] = *(const bf16x8*)&As1[mb + i*16 + lane16][quad*8];
      #pragma unroll
      for (int j = 0; j < 4; ++j)
        bfr[j] = *(const bf16x8*)&Bs1[nb + j*16 + lane16][quad*8];
      #pragma unroll
      for (int i = 0; i < 4; ++i)
        #pragma unroll
        for (int j = 0; j < 4; ++j)
          acc[i][j] = __builtin_amdgcn_mfma_f32_16x16x32_bf16(af[i], bfr[j], acc[i][j], 0, 0, 0);
    }
    __syncthreads();
  }
  #pragma unroll
  for (int i = 0; i < 4; ++i)
    #pragma unroll
    for (int j = 0; j < 4; ++j)
      #pragma unroll
      for (int r = 0; r < 4; ++r) {
        int m = row0 + mb + i*16 + quad*4 + r;
        int n = col0 + nb + j*16 + lane16;
        float v = acc[i][j][r];
        if (MODE == 0) {
          Cf[(size_t)m*N + n] = v;
        } else {
          if (col0 < 1024)       Cq[(size_t)m*1024 + n] = __float2bfloat16(v);
          else if (col0 < 1536)  Cf[(size_t)m*512  + n - 1024] = v;
          else                   Cv[(size_t)m*2048 + n - 1536] = __float2bfloat16(v);
        }
      }
}

// ---------------- fused: G = cumsum(log_sigmoid(pre + b)/16) in place on Gb ----
__global__ __launch_bounds__(256) void gkcumsum_kernel(float* __restrict__ Gb,
                                                       const float* __restrict__ bias) {
  __shared__ float buf[CHUNKC][128];
  const int cs = blockIdx.x & 3;
  const int nc = (blockIdx.x >> 2) & 31;
  const int b  = blockIdx.x >> 7;
  const int t = threadIdx.x;
  const int bc = b*TDIM + nc*CHUNKC;
  const int col0 = cs*128;
  #pragma unroll
  for (int i = 0; i < 32; ++i) {
    int idx = t + 256*i;
    int c = idx >> 7, col = idx & 127;
    float s = Gb[(size_t)(bc + c)*KD + col0 + col] + bias[col0 + col];
    float ls = fminf(s, 0.f) - log1pf(expf(-fabsf(s)));
    buf[c][col] = ls * (1.0f/16.0f);
  }
  __syncthreads();
  if (t < 128) {
    float acc = 0.f;
    #pragma unroll
    for (int c = 0; c < CHUNKC; ++c) {
      acc += buf[c][t];
      buf[c][t] = acc;
    }
  }
  __syncthreads();
  #pragma unroll
  for (int i = 0; i < 32; ++i) {
    int idx = t + 256*i;
    int c = idx >> 7, col = idx & 127;
    Gb[(size_t)(bc + c)*KD + col0 + col] = buf[c][col];
  }
}

// ---------------- per-chunk state increment (MFMA): U[v][k] bf16 ----------------
__global__ __launch_bounds__(256) void state_chunk_kernel(const hbf* __restrict__ qkbf,
                                                          const hbf* __restrict__ vgbf,
                                                          const float* __restrict__ Gb,
                                                          hbf* __restrict__ Ub,
                                                          float* __restrict__ dec) {
  const int bh = blockIdx.x & 7;
  const int nc = blockIdx.x >> 3;
  const int b = bh >> 2, h = bh & 3;
  const int t = threadIdx.x;
  const int w = t >> 6, l = t & 63;
  const int lane16 = l & 15, quad = l >> 4;
  __shared__ hbf kbarT[DK][72];     // [k][c]
  __shared__ hbf vT[DV][72];        // [v][c]
  __shared__ float glast[DK];
  const int bc = b*TDIM + nc*CHUNKC;
  if (t < DK) {
    float gl = Gb[(size_t)(bc + 63)*KD + h*DK + t];
    glast[t] = gl;
    dec[((size_t)nc*8 + bh)*DK + t] = expf(gl);
  }
  __syncthreads();
  #pragma unroll
  for (int i = 0; i < 32; ++i) {
    int idx = t + 256*i;
    int c = idx >> 7, kk = idx & 127;
    float g  = Gb[(size_t)(bc + c)*KD + h*DK + kk];
    float kv = __bfloat162float(qkbf[(size_t)(bc + c)*1024 + 512 + h*DK + kk]);
    kbarT[kk][c] = __float2bfloat16(kv * expf(glast[kk] - g));
  }
  #pragma unroll
  for (int i = 0; i < 64; ++i) {
    int idx = t + 256*i;
    int c = idx >> 8, col = idx & 255;
    vT[col][c] = vgbf[(size_t)(bc + c)*2048 + h*DV + col];
  }
  __syncthreads();
  f32x4 acc[4][8] = {};
  #pragma unroll
  for (int kc = 0; kc < 2; ++kc) {
    bf16x8 av[4], bk[8];
    #pragma unroll
    for (int i = 0; i < 4; ++i)
      av[i] = *(const bf16x8*)&vT[w*64 + i*16 + lane16][kc*32 + quad*8];
    #pragma unroll
    for (int j = 0; j < 8; ++j)
      bk[j] = *(const bf16x8*)&kbarT[j*16 + lane16][kc*32 + quad*8];
    #pragma unroll
    for (int i = 0; i < 4; ++i)
      #pragma unroll
      for (int j = 0; j < 8; ++j)
        acc[i][j] = __builtin_amdgcn_mfma_f32_16x16x32_bf16(av[i], bk[j], acc[i][j], 0, 0, 0);
  }
  hbf* ub = Ub + ((size_t)nc*8 + bh)*((size_t)DK*DV);
  #pragma unroll
  for (int i = 0; i < 4; ++i)
    #pragma unroll
    for (int j = 0; j < 8; ++j)
      #pragma unroll
      for (int r = 0; r < 4; ++r) {
        int v = w*64 + i*16 + quad*4 + r;
        int k = j*16 + lane16;
        ub[(size_t)v*DK + k] = __float2bfloat16(acc[i][j][r]);
      }
}

// ---------------- scan over chunks: reads U bf16, fp32 accum, writes S_prev bf16 ----
__global__ __launch_bounds__(256) void state_scan_kernel(const hbf* __restrict__ Ub,
                                                         const float* __restrict__ dec,
                                                         hbf* __restrict__ Spb) {
  const int p = blockIdx.x*256 + threadIdx.x;   // pair index 0..131071
  const size_t e = (size_t)p*2;
  const int k = (int)(e & 127);
  const int bh = (int)(e >> 15);
  float S0 = 0.f, S1 = 0.f;
  for (int nc = 0; nc < NC; ++nc) {
    const size_t off = (size_t)nc*STRIDE_ST + e;
    uint uu = *(const uint*)(Ub + off);
    hbf u0 = *(const hbf*)&uu;
    hbf u1 = *((const hbf*)&uu + 1);
    union { hbf h[2]; uint u; } ov;
    ov.h[0] = __float2bfloat16(S0); ov.h[1] = __float2bfloat16(S1);
    *(uint*)(Spb + off) = ov.u;
    float2 d = *(const float2*)(dec + ((size_t)nc*8 + bh)*DK + k);
    S0 = S0 * d.x + __bfloat162float(u0);
    S1 = S1 * d.y + __bfloat162float(u1);
  }
}

// ---------------- per-chunk output (MFMA): tril(qg kg^T), qg@S + A@v, RMSNorm, gate ----
__global__ __launch_bounds__(256) void out_kernel(const hbf* __restrict__ qkbf,
                                                  const hbf* __restrict__ vgbf,
                                                  const float* __restrict__ Gb,
                                                  const hbf* __restrict__ Spb,
                                                  const float* __restrict__ gnw,
                                                  hbf* __restrict__ obf) {
  const int blk = blockIdx.x;
  const int h = blk & 3, b = (blk >> 2) & 1, nc = blk >> 3;
  const int t = threadIdx.x;
  const int w = t >> 6, l = t & 63;
  const int lane16 = l & 15, quad = l >> 4;

  __shared__ __align__(16) unsigned char smem[64768];
  hbf (*qgs)[136] = (hbf(*)[136])(smem);                 // 17408 B
  hbf (*Ald)[72]  = (hbf(*)[72]) (smem + 17408);         //  9216 B
  hbf (*kgs)[136] = (hbf(*)[136])(smem + 26624);         // 17408 B (phase 1)
  hbf (*vT)[72]   = (hbf(*)[72]) (smem + 26624);         // 36864 B (phase 2, aliases kgs)
  float* ssum     = (float*)     (smem + 63488);         // 64*4
  float* invb     = (float*)     (smem + 64512);         // 64

  const float scale = 0.088388347648318447f;  // 128^-0.5
  const int bc = b*TDIM + nc*CHUNKC;

  #pragma unroll
  for (int i = 0; i < 32; ++i) {
    int idx = t + 256*i;
    int c = idx >> 7, kk = idx & 127;
    float g = Gb[(size_t)(bc + c)*KD + h*DK + kk];
    float qv = __bfloat162float(qkbf[(size_t)(bc + c)*1024 + h*DK + kk]);
    float kv = __bfloat162float(qkbf[(size_t)(bc + c)*1024 + 512 + h*DK + kk]);
    qgs[c][kk] = __float2bfloat16(qv * expf(g) * scale);
    kgs[c][kk] = __float2bfloat16(kv * expf(-g));
  }
  __syncthreads();

  f32x4 acc1[4] = {};
  #pragma unroll
  for (int kc = 0; kc < 4; ++kc) {
    bf16x8 af = *(const bf16x8*)&qgs[w*16 + lane16][kc*32 + quad*8];
    #pragma unroll
    for (int j = 0; j < 4; ++j) {
      bf16x8 bf = *(const bf16x8*)&kgs[j*16 + lane16][kc*32 + quad*8];
      acc1[j] = __builtin_amdgcn_mfma_f32_16x16x32_bf16(af, bf, acc1[j], 0, 0, 0);
    }
  }
  __syncthreads();

  #pragma unroll
  for (int j = 0; j < 4; ++j)
    #pragma unroll
    for (int r = 0; r < 4; ++r) {
      int cr = w*16 + quad*4 + r;
      int cc = j*16 + lane16;
      Ald[cr][cc] = __float2bfloat16(cc <= cr ? acc1[j][r] : 0.f);
    }
  #pragma unroll
  for (int i = 0; i < 64; ++i) {
    int e = t + 256*i;
    int c = e >> 8, col = e & 255;
    vT[col][c] = vgbf[(size_t)(bc + c)*2048 + h*DV + col];
  }
  __syncthreads();

  const hbf* SpB = Spb + ((size_t)nc*8 + (b*HH + h))*((size_t)DK*DV);
  f32x4 acc[4][4] = {};
  #pragma unroll
  for (int kc = 0; kc < 4; ++kc) {
    bf16x8 af[4], bs[4];
    #pragma unroll
    for (int i = 0; i < 4; ++i)
      af[i] = *(const bf16x8*)&qgs[i*16 + lane16][kc*32 + quad*8];
    #pragma unroll
    for (int j = 0; j < 4; ++j) {
      int n = w*64 + j*16 + lane16;
      bs[j] = *(const bf16x8*)(SpB + (size_t)n*DK + kc*32 + quad*8);
    }
    #pragma unroll
    for (int i = 0; i < 4; ++i)
      #pragma unroll
      for (int j = 0; j < 4; ++j)
        acc[i][j] = __builtin_amdgcn_mfma_f32_16x16x32_bf16(af[i], bs[j], acc[i][j], 0, 0, 0);
  }
  #pragma unroll
  for (int kc = 0; kc < 2; ++kc) {
    bf16x8 aa[4], bv[4];
    #pragma unroll
    for (int i = 0; i < 4; ++i)
      aa[i] = *(const bf16x8*)&Ald[i*16 + lane16][kc*32 + quad*8];
    #pragma unroll
    for (int j = 0; j < 4; ++j)
      bv[j] = *(const bf16x8*)&vT[w*64 + j*16 + lane16][kc*32 + quad*8];
    #pragma unroll
    for (int i = 0; i < 4; ++i)
      #pragma unroll
      for (int j = 0; j < 4; ++j)
        acc[i][j] = __builtin_amdgcn_mfma_f32_16x16x32_bf16(aa[i], bv[j], acc[i][j], 0, 0, 0);
  }

  #pragma unroll
  for (int i = 0; i < 4; ++i)
    #pragma unroll
    for (int r = 0; r < 4; ++r) {
      float s = 0.f;
      #pragma unroll
      for (int j = 0; j < 4; ++j) s += acc[i][j][r]*acc[i][j][r];
      s += __shfl_xor(s, 1); s += __shfl_xor(s, 2);
      s += __shfl_xor(s, 4); s += __shfl_xor(s, 8);
      if (lane16 == 0) ssum[(i*16 + quad*4 + r)*4 + w] = s;
    }
  __syncthreads();
  if (t < 64) {
    float tot = ssum[t*4] + ssum[t*4+1] + ssum[t*4+2] + ssum[t*4+3];
    invb[t] = rsqrtf(tot * (1.0f/DV) + 1e-6f);
  }
  __syncthreads();
  float gnwv[4];
  #pragma unroll
  for (int j = 0; j < 4; ++j) gnwv[j] = gnw[w*64 + j*16 + lane16];
  #pragma unroll
  for (int i = 0; i < 4; ++i)
    #pragma unroll
    for (int r = 0; r < 4; ++r) {
      int m = i*16 + quad*4 + r;
      float inv = invb[m];
      size_t grow_ = (size_t)(bc + m)*2048 + 1024 + h*DV + w*64;
      size_t orow_ = (size_t)(bc + m)*VD + h*DV + w*64;
      #pragma unroll
      for (int j = 0; j < 4; ++j) {
        float gv = __bfloat162float(vgbf[grow_ + j*16 + lane16]);
        float sig = 1.f / (1.f + expf(-gv));
        float val = acc[i][j][r] * inv * gnwv[j];
        obf[orow_ + j*16 + lane16] = __float2bfloat16(val * (gv * sig));
      }
    }
}

extern "C" void kernel_launch(void* const* d_in, const int* in_sizes, int n_in,
                              void* d_out, int out_size, void* d_ws, size_t ws_size,
                              hipStream_t stream) {
  const float* x    = (const float*)d_in[0];
  const float* Wq   = (const float*)d_in[1];
  const float* Wk   = (const float*)d_in[2];
  const float* Wv   = (const float*)d_in[3];
  const float* Wg   = (const float*)d_in[4];
  const float* Wgk1 = (const float*)d_in[5];
  const float* Wgk2 = (const float*)d_in[6];
  const float* bgk2 = (const float*)d_in[7];
  const float* gnw  = (const float*)d_in[8];
  const float* Wo   = (const float*)d_in[9];
  float* out = (float*)d_out;

  float* ws  = (float*)d_ws;
  float* Gb  = ws;                                   // 4096*512 fp32 (gk pre -> G)
  float* dec = Gb  + (size_t)MTOT*KD;                // 32*8*128 fp32
  hbf* xbf   = (hbf*)(dec + (size_t)NC*BDIM*HH*DK);  // 4096*1024 bf16
  hbf* wtall = xbf   + (size_t)MTOT*DDIM;            // 3584*1024 bf16 (Wq|Wk|Wc|Wv|Wg)^T
  hbf* wto   = wtall + (size_t)NALL*DDIM;            // 1024*1024 bf16
  hbf* qkbf  = wto   + (size_t)DDIM*DDIM;            // 4096*1024 bf16 (q|k)
  hbf* vgbf  = qkbf  + (size_t)MTOT*1024;            // 4096*2048 bf16 (v|g)
  hbf* Ub    = vgbf  + (size_t)MTOT*2048;            // 32*262144 bf16 (U, [v][k])
  hbf* Spb   = Ub    + (size_t)NC*STRIDE_ST;         // 32*262144 bf16 (S_prev, [v][k])
  hbf* obf   = Ub;                                   // alias: U dead before out_kernel

  cast_bf16_kernel<<<MTOT*DDIM/4/256, 256, 0, stream>>>(x, xbf);
  prep_weights<<<dim3(144, 32), 256, 0, stream>>>(Wq, Wk, Wv, Wg, Wo, Wgk1, Wgk2, wtall, wto);

  gemm_bt<1><<<dim3(NALL/128, MTOT/128), 256, 0, stream>>>(xbf, wtall, Gb, qkbf, vgbf, MTOT, NALL, DDIM);

  gkcumsum_kernel<<<256, 256, 0, stream>>>(Gb, bgk2);
  state_chunk_kernel<<<NC*BDIM*HH, 256, 0, stream>>>(qkbf, vgbf, Gb, Ub, dec);
  state_scan_kernel<<<(int)(STRIDE_ST/2/256), 256, 0, stream>>>(Ub, dec, Spb);
  out_kernel<<<NC*BDIM*HH, 256, 0, stream>>>(qkbf, vgbf, Gb, Spb, gnw, obf);
  gemm_bt<0><<<dim3(DDIM/128, MTOT/128), 256, 0, stream>>>(obf, wto, out, (hbf*)nullptr, (hbf*)nullptr, MTOT, DDIM, DDIM);
}